// Round 1
// baseline (1122.980 us; speedup 1.0000x reference)
//
#include <hip/hip_runtime.h>
#include <cstdint>
#include <cstddef>
#include <math.h>

#define N_NODES 40000
#define N_RELS  474
#define E0      100000   // edge_list edges
#define EN      30000    // nhop edges
#define NE      130000   // total
#define NB      8192     // batch rows
#define LRALPHA 0.2f

// ---------------- row L2 normalize (wave per row) ----------------
__global__ void k_l2norm(const float* __restrict__ in, float* __restrict__ out, int M, int F) {
    int w = (blockIdx.x * blockDim.x + threadIdx.x) >> 6;
    int lane = threadIdx.x & 63;
    if (w >= M) return;
    const float* r = in + (size_t)w * F;
    float ss = 0.f;
    for (int j = lane; j < F; j += 64) { float v = r[j]; ss += v * v; }
#pragma unroll
    for (int o = 32; o > 0; o >>= 1) ss += __shfl_down(ss, o);
    ss = __shfl(ss, 0);
    float inv = 1.f / fmaxf(sqrtf(ss), 1e-12f);
    float* dst = out + (size_t)w * F;
    for (int j = lane; j < F; j += 64) dst[j] = r[j] * inv;
}

// ---------------- generic tiled fp32 matmul ----------------
// BT=true : C[m,n] = sum_k A[m*lda+k] * B[n*ldb+k]
// BT=false: C[m,n] = sum_k A[m*lda+k] * B[k*ldb+n]
template <bool BT>
__global__ __launch_bounds__(256) void k_mm(const float* __restrict__ A, int lda,
                                            const float* __restrict__ B, int ldb,
                                            float* __restrict__ C, int ldc,
                                            int M, int N, int K) {
    __shared__ float As[16][65];
    __shared__ float Bs[16][65];
    int tid = threadIdx.x;
    int tx = tid & 15, ty = tid >> 4;
    int m0 = blockIdx.y * 64, n0 = blockIdx.x * 64;
    float acc[4][4] = {};
    for (int k0 = 0; k0 < K; k0 += 16) {
        {   // A tile: 64 rows x 16 k
            int r = tid >> 2;
            int c4 = (tid & 3) * 4;
            int m = m0 + r;
#pragma unroll
            for (int u = 0; u < 4; u++) {
                int k = k0 + c4 + u;
                As[c4 + u][r] = (m < M && k < K) ? A[(size_t)m * lda + k] : 0.f;
            }
        }
        if (BT) {
            int r = tid >> 2;
            int c4 = (tid & 3) * 4;
            int n = n0 + r;
#pragma unroll
            for (int u = 0; u < 4; u++) {
                int k = k0 + c4 + u;
                Bs[c4 + u][r] = (n < N && k < K) ? B[(size_t)n * ldb + k] : 0.f;
            }
        } else {
            int kk = tid >> 4;
            int nn4 = (tid & 15) * 4;
            int k = k0 + kk;
#pragma unroll
            for (int u = 0; u < 4; u++) {
                int n = n0 + nn4 + u;
                Bs[kk][nn4 + u] = (k < K && n < N) ? B[(size_t)k * ldb + n] : 0.f;
            }
        }
        __syncthreads();
#pragma unroll
        for (int k = 0; k < 16; k++) {
            float a[4], b[4];
#pragma unroll
            for (int i = 0; i < 4; i++) a[i] = As[k][ty + 16 * i];
#pragma unroll
            for (int j = 0; j < 4; j++) b[j] = Bs[k][tx + 16 * j];
#pragma unroll
            for (int i = 0; i < 4; i++)
#pragma unroll
                for (int j = 0; j < 4; j++) acc[i][j] += a[i] * b[j];
        }
        __syncthreads();
    }
#pragma unroll
    for (int i = 0; i < 4; i++) {
        int m = m0 + ty + 16 * i;
        if (m >= M) continue;
#pragma unroll
        for (int j = 0; j < 4; j++) {
            int n = n0 + tx + 16 * j;
            if (n < N) C[(size_t)m * ldc + n] = acc[i][j];
        }
    }
}

// ---------------- per-row dot with vector (wave per row) ----------------
__global__ void k_dotv(const float* __restrict__ mat, const float* __restrict__ vec,
                       float* __restrict__ out, int M, int F) {
    int w = (blockIdx.x * blockDim.x + threadIdx.x) >> 6;
    int lane = threadIdx.x & 63;
    if (w >= M) return;
    const float* r = mat + (size_t)w * F;
    float s = 0.f;
    for (int j = lane; j < F; j += 64) s += r[j] * vec[j];
#pragma unroll
    for (int o = 32; o > 0; o >>= 1) s += __shfl_down(s, o);
    if (lane == 0) out[w] = s;
}

// ---------------- CSR build ----------------
__global__ void k_hist(const int* __restrict__ tgt_el, const int* __restrict__ nhop,
                       int* __restrict__ deg) {
    int e = blockIdx.x * blockDim.x + threadIdx.x;
    if (e >= NE) return;
    int t = (e < E0) ? tgt_el[e] : nhop[(size_t)(e - E0) * 4 + 3];
    atomicAdd(&deg[t], 1);
}

__global__ void k_scan(const int* __restrict__ deg, int* __restrict__ rowptr,
                       int* __restrict__ cursor, int n) {
    __shared__ int tmp[256];
    __shared__ int carry;
    int tid = threadIdx.x;
    if (tid == 0) carry = 0;
    __syncthreads();
    for (int base = 0; base < n; base += 256) {
        int i = base + tid;
        int v = (i < n) ? deg[i] : 0;
        tmp[tid] = v;
        __syncthreads();
        for (int o = 1; o < 256; o <<= 1) {
            int t = (tid >= o) ? tmp[tid - o] : 0;
            __syncthreads();
            tmp[tid] += t;
            __syncthreads();
        }
        int excl = carry + tmp[tid] - v;
        if (i < n) { rowptr[i] = excl; cursor[i] = excl; }
        __syncthreads();
        if (tid == 255) carry += tmp[255];
        __syncthreads();
    }
    if (tid == 0) rowptr[n] = carry;
}

__global__ void k_scatter(const int* __restrict__ tgt_el, const int* __restrict__ nhop,
                          int* __restrict__ cursor, int* __restrict__ eidx) {
    int e = blockIdx.x * blockDim.x + threadIdx.x;
    if (e >= NE) return;
    int t = (e < E0) ? tgt_el[e] : nhop[(size_t)(e - E0) * 4 + 3];
    int p = atomicAdd(&cursor[t], 1);
    eidx[p] = e;
}

// ---------------- per-edge attention scalar, layer 1 (both heads) ----------------
__global__ void k_edge1(const int* __restrict__ tgt_el, const int* __restrict__ src_el,
                        const int* __restrict__ etype, const int* __restrict__ nhop,
                        const float* __restrict__ dpt0, const float* __restrict__ dps0,
                        const float* __restrict__ dR0,
                        const float* __restrict__ dpt1, const float* __restrict__ dps1,
                        const float* __restrict__ dR1,
                        float* __restrict__ w0, float* __restrict__ w1) {
    int e = blockIdx.x * blockDim.x + threadIdx.x;
    if (e >= NE) return;
    int t, s; float dr0, dr1;
    if (e < E0) {
        t = tgt_el[e]; s = src_el[e];
        int r = etype[e];
        dr0 = dR0[r]; dr1 = dR1[r];
    } else {
        const int* nh = nhop + (size_t)(e - E0) * 4;
        t = nh[3]; s = nh[0];
        dr0 = dR0[nh[1]] + dR0[nh[2]];
        dr1 = dR1[nh[1]] + dR1[nh[2]];
    }
    float p0 = dpt0[t] + dps0[s] + dr0;
    float p1 = dpt1[t] + dps1[s] + dr1;
    p0 = (p0 >= 0.f) ? p0 : LRALPHA * p0;
    p1 = (p1 >= 0.f) ? p1 : LRALPHA * p1;
    w0[e] = expf(-p0);
    w1[e] = expf(-p1);
}

// ---------------- per-edge attention scalar, layer 2 ----------------
__global__ void k_edge2(const int* __restrict__ tgt_el, const int* __restrict__ src_el,
                        const int* __restrict__ etype, const int* __restrict__ nhop,
                        const float* __restrict__ dqt, const float* __restrict__ dqs,
                        const float* __restrict__ dR2, float* __restrict__ w2) {
    int e = blockIdx.x * blockDim.x + threadIdx.x;
    if (e >= NE) return;
    int t, s; float dr;
    if (e < E0) {
        t = tgt_el[e]; s = src_el[e];
        dr = dR2[etype[e]];
    } else {
        const int* nh = nhop + (size_t)(e - E0) * 4;
        t = nh[3]; s = nh[0];
        dr = dR2[nh[1]] + dR2[nh[2]];
    }
    float p = dqt[t] + dqs[s] + dr;
    p = (p >= 0.f) ? p : LRALPHA * p;
    w2[e] = expf(-p);
}

// ---------------- node aggregation layer 1, both heads fused (wave/node) ----------------
__global__ void k_node1(const int* __restrict__ rowptr, const int* __restrict__ eidx,
                        const int* __restrict__ src_el, const int* __restrict__ etype,
                        const int* __restrict__ nhop,
                        const float* __restrict__ Ps0, const float* __restrict__ Ps1,
                        const float* __restrict__ Pt0, const float* __restrict__ Pt1,
                        const float* __restrict__ R10, const float* __restrict__ R11,
                        const float* __restrict__ w0, const float* __restrict__ w1,
                        float* __restrict__ x) {
    int node = (blockIdx.x * blockDim.x + threadIdx.x) >> 6;
    int lane = threadIdx.x & 63;
    if (node >= N_NODES) return;
    int j1 = lane + 64;
    bool v1 = (j1 < 100);
    float a00 = 0, a01 = 0, a10 = 0, a11 = 0, rs0 = 0, rs1 = 0;
    int beg = rowptr[node], end = rowptr[node + 1];
    for (int p = beg; p < end; p++) {
        int e = eidx[p];
        int s; float r00, r01, r10, r11;
        if (e < E0) {
            s = src_el[e];
            int t = etype[e];
            const float* q0 = R10 + (size_t)t * 100;
            const float* q1 = R11 + (size_t)t * 100;
            r00 = q0[lane]; r01 = v1 ? q0[j1] : 0.f;
            r10 = q1[lane]; r11 = v1 ? q1[j1] : 0.f;
        } else {
            const int* nh = nhop + (size_t)(e - E0) * 4;
            s = nh[0];
            const float* q0a = R10 + (size_t)nh[1] * 100;
            const float* q0b = R10 + (size_t)nh[2] * 100;
            const float* q1a = R11 + (size_t)nh[1] * 100;
            const float* q1b = R11 + (size_t)nh[2] * 100;
            r00 = q0a[lane] + q0b[lane]; r01 = v1 ? (q0a[j1] + q0b[j1]) : 0.f;
            r10 = q1a[lane] + q1b[lane]; r11 = v1 ? (q1a[j1] + q1b[j1]) : 0.f;
        }
        float W0 = w0[e], W1 = w1[e];
        rs0 += W0; rs1 += W1;
        const float* ps0 = Ps0 + (size_t)s * 100;
        const float* ps1 = Ps1 + (size_t)s * 100;
        a00 += W0 * (ps0[lane] + r00);
        a10 += W1 * (ps1[lane] + r10);
        if (v1) {
            a01 += W0 * (ps0[j1] + r01);
            a11 += W1 * (ps1[j1] + r11);
        }
    }
    float d0 = (rs0 == 0.f) ? 1e-12f : rs0;
    float d1 = (rs1 == 0.f) ? 1e-12f : rs1;
    const float* pt0 = Pt0 + (size_t)node * 100;
    const float* pt1 = Pt1 + (size_t)node * 100;
    float* xr = x + (size_t)node * 200;
    float v = (a00 + rs0 * pt0[lane]) / d0;
    xr[lane] = (v > 0.f) ? v : expm1f(v);
    float u = (a10 + rs1 * pt1[lane]) / d1;
    xr[100 + lane] = (u > 0.f) ? u : expm1f(u);
    if (v1) {
        float v2 = (a01 + rs0 * pt0[j1]) / d0;
        xr[j1] = (v2 > 0.f) ? v2 : expm1f(v2);
        float u2 = (a11 + rs1 * pt1[j1]) / d1;
        xr[100 + j1] = (u2 > 0.f) ? u2 : expm1f(u2);
    }
}

// ---------------- node aggregation layer 2 + final fuse (wave/node) ----------------
__global__ void k_node2(const int* __restrict__ rowptr, const int* __restrict__ eidx,
                        const int* __restrict__ src_el, const int* __restrict__ etype,
                        const int* __restrict__ nhop,
                        const float* __restrict__ Qs, const float* __restrict__ Qt,
                        const float* __restrict__ R2, const float* __restrict__ w2,
                        const float* __restrict__ entW, const float* __restrict__ mask,
                        float* __restrict__ out) {
    int node = (blockIdx.x * blockDim.x + threadIdx.x) >> 6;
    int lane = threadIdx.x & 63;
    if (node >= N_NODES) return;
    bool v3 = (lane < 8);
    int j3 = lane + 192;
    float acc0 = 0, acc1 = 0, acc2 = 0, acc3 = 0, rs = 0;
    int beg = rowptr[node], end = rowptr[node + 1];
    for (int p = beg; p < end; p++) {
        int e = eidx[p];
        int s; const float* ra; const float* rb = nullptr;
        if (e < E0) {
            s = src_el[e];
            ra = R2 + (size_t)etype[e] * 200;
        } else {
            const int* nh = nhop + (size_t)(e - E0) * 4;
            s = nh[0];
            ra = R2 + (size_t)nh[1] * 200;
            rb = R2 + (size_t)nh[2] * 200;
        }
        float W = w2[e]; rs += W;
        const float* qs = Qs + (size_t)s * 200;
        float r0 = ra[lane], r1 = ra[lane + 64], r2 = ra[lane + 128];
        float r3 = v3 ? ra[j3] : 0.f;
        if (rb) {
            r0 += rb[lane]; r1 += rb[lane + 64]; r2 += rb[lane + 128];
            if (v3) r3 += rb[j3];
        }
        acc0 += W * (qs[lane] + r0);
        acc1 += W * (qs[lane + 64] + r1);
        acc2 += W * (qs[lane + 128] + r2);
        if (v3) acc3 += W * (qs[j3] + r3);
    }
    float d = (rs == 0.f) ? 1e-12f : rs;
    const float* qt = Qt + (size_t)node * 200;
    const float* ew = entW + (size_t)node * 200;
    float mk = mask[node];
    float val0 = ew[lane]       + mk * ((acc0 + rs * qt[lane]) / d);
    float val1 = ew[lane + 64]  + mk * ((acc1 + rs * qt[lane + 64]) / d);
    float val2 = ew[lane + 128] + mk * ((acc2 + rs * qt[lane + 128]) / d);
    float val3 = v3 ? (ew[j3] + mk * ((acc3 + rs * qt[j3]) / d)) : 0.f;
    float ss = val0 * val0 + val1 * val1 + val2 * val2 + val3 * val3;
#pragma unroll
    for (int o = 32; o > 0; o >>= 1) ss += __shfl_down(ss, o);
    ss = __shfl(ss, 0);
    float inv = 1.f / fmaxf(sqrtf(ss), 1e-12f);
    float* dst = out + (size_t)node * 200;
    dst[lane] = val0 * inv;
    dst[lane + 64] = val1 * inv;
    dst[lane + 128] = val2 * inv;
    if (v3) dst[j3] = val3 * inv;
}

// ---------------- mask scatter ----------------
__global__ void k_mask(const int* __restrict__ batch, float* __restrict__ mask) {
    int i = blockIdx.x * blockDim.x + threadIdx.x;
    if (i < NB) mask[batch[(size_t)i * 3 + 2]] = 1.0f;
}

// ---------------- ortho losses (single block) ----------------
__global__ void k_ortho(const float* __restrict__ att_a, const float* __restrict__ out_a,
                        float* __restrict__ out_scalar) {
    __shared__ float r0[4], r1[4], rc[4];
    int tid = threadIdx.x, lane = tid & 63, wv = tid >> 6;
    float total = 0.f;
    for (int m = 0; m < 3; m++) {
        const float* base; int L;
        if (m == 0)      { base = att_a;          L = 15000; }
        else if (m == 1) { base = att_a + 30000;  L = 15000; }
        else             { base = out_a;          L = 60000; }
        float s0 = 0.f, s1 = 0.f, sc = 0.f;
        for (int i = tid; i < L; i += 256) {
            float a = base[i], b = base[L + i];
            s0 += a * a; s1 += b * b; sc += a * b;
        }
#pragma unroll
        for (int o = 32; o > 0; o >>= 1) {
            s0 += __shfl_down(s0, o);
            s1 += __shfl_down(s1, o);
            sc += __shfl_down(sc, o);
        }
        if (lane == 0) { r0[wv] = s0; r1[wv] = s1; rc[wv] = sc; }
        __syncthreads();
        if (tid == 0) {
            float t0 = 0, t1 = 0, tc = 0;
            for (int k = 0; k < 4; k++) { t0 += r0[k]; t1 += r1[k]; tc += rc[k]; }
            float c = tc / (fmaxf(sqrtf(t0), 1e-12f) * fmaxf(sqrtf(t1), 1e-12f));
            total += 0.01f * 2.f * c * c;   // lambda * (2 off-diagonal c^2); diagonal terms are 0
        }
        __syncthreads();
    }
    if (tid == 0) out_scalar[0] = total;
}

// ---------------- launch ----------------
extern "C" void kernel_launch(void* const* d_in, const int* in_sizes, int n_in,
                              void* d_out, int out_size, void* d_ws, size_t ws_size,
                              hipStream_t stream) {
    const int* edge_list = (const int*)d_in[0];   // [2][E0]
    const int* edge_type = (const int*)d_in[1];   // [E0]
    const int* batch     = (const int*)d_in[2];   // [NB][3]
    const int* nhop      = (const int*)d_in[3];   // [EN][4]
    const float* ent_emb = (const float*)d_in[4]; // [40000][100]
    const float* rel_emb = (const float*)d_in[5]; // [474][100]
    const float* W_ent   = (const float*)d_in[6]; // [100][200]
    const float* W_rel   = (const float*)d_in[7]; // [100][200]
    const float* att_a   = (const float*)d_in[8]; // [2][100][300]
    const float* att_a2  = (const float*)d_in[9]; // [2][100]
    const float* out_a   = (const float*)d_in[10];// [200][600]
    const float* out_a2  = (const float*)d_in[11];// [200]
    float* out = (float*)d_out;
    const int* tgt_el = edge_list;
    const int* src_el = edge_list + E0;

    // workspace carve-up (256B aligned)
    char* ws = (char*)d_ws;
    size_t o = 0;
    auto alloc = [&](size_t nbytes) -> char* {
        char* p = ws + o;
        o += (nbytes + 255) & ~(size_t)255;
        return p;
    };
    float* ent  = (float*)alloc(40000u * 100 * 4);
    float* Pt0  = (float*)alloc(40000u * 100 * 4);  // layer2: Qt spans Pt0+Ps0
    float* Ps0  = (float*)alloc(40000u * 100 * 4);
    float* Pt1  = (float*)alloc(40000u * 100 * 4);  // layer2: Qs spans Pt1+Ps1
    float* Ps1  = (float*)alloc(40000u * 100 * 4);
    float* xbuf = (float*)alloc(40000u * 200 * 4);  // x, then entW
    float* R10  = (float*)alloc(474u * 100 * 4);
    float* R11  = (float*)alloc(474u * 100 * 4);
    float* R2   = (float*)alloc(474u * 200 * 4);
    float* dpt0 = (float*)alloc(40000u * 4);
    float* dps0 = (float*)alloc(40000u * 4);
    float* dpt1 = (float*)alloc(40000u * 4);
    float* dps1 = (float*)alloc(40000u * 4);
    float* dqt  = (float*)alloc(40000u * 4);
    float* dqs  = (float*)alloc(40000u * 4);
    float* dR10 = (float*)alloc(474u * 4);
    float* dR11 = (float*)alloc(474u * 4);
    float* dR2  = (float*)alloc(474u * 4);
    float* w0   = (float*)alloc((size_t)NE * 4);
    float* w1   = (float*)alloc((size_t)NE * 4);
    float* w2   = (float*)alloc((size_t)NE * 4);
    int* rowptr = (int*)alloc((N_NODES + 1) * 4);
    int* cursor = (int*)alloc(N_NODES * 4);
    int* eidx   = (int*)alloc((size_t)NE * 4);
    float* mask = (float*)alloc(N_NODES * 4);
    float* Qt = Pt0;      // 40000x200 reuse (layer-1 P dead by then)
    float* Qs = Pt1;
    float* entW = xbuf;   // overwrite x after Qt/Qs matmuls

    const int TPB = 256;
    int wave_blocks_40000 = (N_NODES * 64 + TPB - 1) / TPB;   // 10000
    int wave_blocks_474   = (N_RELS * 64 + TPB - 1) / TPB;    // 119
    int edge_blocks       = (NE + TPB - 1) / TPB;

    // zero deg (cursor) and mask
    hipMemsetAsync(cursor, 0, N_NODES * 4, stream);
    hipMemsetAsync(mask, 0, N_NODES * 4, stream);

    // 1) normalize entities
    k_l2norm<<<wave_blocks_40000, TPB, 0, stream>>>(ent_emb, ent, N_NODES, 100);

    // 2) CSR by target (shared by all 3 aggregation passes)
    k_hist<<<edge_blocks, TPB, 0, stream>>>(tgt_el, nhop, cursor);
    k_scan<<<1, TPB, 0, stream>>>(cursor, rowptr, cursor, N_NODES);
    k_scatter<<<edge_blocks, TPB, 0, stream>>>(tgt_el, nhop, cursor, eidx);

    // 3) layer-1 projections: P = ent @ a_part^T, R = rel_emb @ a_r^T
    dim3 g1((100 + 63) / 64, (N_NODES + 63) / 64);
    k_mm<true><<<g1, TPB, 0, stream>>>(ent, 100, att_a + 0,     300, Pt0, 100, N_NODES, 100, 100);
    k_mm<true><<<g1, TPB, 0, stream>>>(ent, 100, att_a + 100,   300, Ps0, 100, N_NODES, 100, 100);
    k_mm<true><<<g1, TPB, 0, stream>>>(ent, 100, att_a + 30000, 300, Pt1, 100, N_NODES, 100, 100);
    k_mm<true><<<g1, TPB, 0, stream>>>(ent, 100, att_a + 30100, 300, Ps1, 100, N_NODES, 100, 100);
    dim3 gr1((100 + 63) / 64, (N_RELS + 63) / 64);
    k_mm<true><<<gr1, TPB, 0, stream>>>(rel_emb, 100, att_a + 200,   300, R10, 100, N_RELS, 100, 100);
    k_mm<true><<<gr1, TPB, 0, stream>>>(rel_emb, 100, att_a + 30200, 300, R11, 100, N_RELS, 100, 100);

    // 4) logit decompositions
    k_dotv<<<wave_blocks_40000, TPB, 0, stream>>>(Pt0, att_a2,       dpt0, N_NODES, 100);
    k_dotv<<<wave_blocks_40000, TPB, 0, stream>>>(Ps0, att_a2,       dps0, N_NODES, 100);
    k_dotv<<<wave_blocks_40000, TPB, 0, stream>>>(Pt1, att_a2 + 100, dpt1, N_NODES, 100);
    k_dotv<<<wave_blocks_40000, TPB, 0, stream>>>(Ps1, att_a2 + 100, dps1, N_NODES, 100);
    k_dotv<<<wave_blocks_474, TPB, 0, stream>>>(R10, att_a2,       dR10, N_RELS, 100);
    k_dotv<<<wave_blocks_474, TPB, 0, stream>>>(R11, att_a2 + 100, dR11, N_RELS, 100);

    // 5) per-edge weights, layer 1 (both heads)
    k_edge1<<<edge_blocks, TPB, 0, stream>>>(tgt_el, src_el, edge_type, nhop,
                                             dpt0, dps0, dR10, dpt1, dps1, dR11, w0, w1);

    // 6) layer-1 aggregation -> x (40000x200)
    k_node1<<<wave_blocks_40000, TPB, 0, stream>>>(rowptr, eidx, src_el, edge_type, nhop,
                                                   Ps0, Ps1, Pt0, Pt1, R10, R11, w0, w1, xbuf);

    // 7) layer-2 projections
    dim3 g2((200 + 63) / 64, (N_NODES + 63) / 64);
    k_mm<true><<<g2, TPB, 0, stream>>>(xbuf, 200, out_a + 0,   600, Qt, 200, N_NODES, 200, 200);
    k_mm<true><<<g2, TPB, 0, stream>>>(xbuf, 200, out_a + 200, 600, Qs, 200, N_NODES, 200, 200);
    // out_relation_1 = rel_emb @ W_rel  -> directly into d_out
    dim3 gor((200 + 63) / 64, (N_RELS + 63) / 64);
    k_mm<false><<<gor, TPB, 0, stream>>>(rel_emb, 100, W_rel, 200, out + 8000000, 200, N_RELS, 200, 100);
    k_mm<true><<<gor, TPB, 0, stream>>>(out + 8000000, 200, out_a + 400, 600, R2, 200, N_RELS, 200, 200);
    k_dotv<<<wave_blocks_40000, TPB, 0, stream>>>(Qt, out_a2, dqt, N_NODES, 200);
    k_dotv<<<wave_blocks_40000, TPB, 0, stream>>>(Qs, out_a2, dqs, N_NODES, 200);
    k_dotv<<<wave_blocks_474, TPB, 0, stream>>>(R2, out_a2, dR2, N_RELS, 200);

    // 8) per-edge weights, layer 2
    k_edge2<<<edge_blocks, TPB, 0, stream>>>(tgt_el, src_el, edge_type, nhop, dqt, dqs, dR2, w2);

    // 9) entW = ent @ W_entities (overwrites xbuf; x no longer needed)
    k_mm<false><<<g2, TPB, 0, stream>>>(ent, 100, W_ent, 200, entW, 200, N_NODES, 200, 100);

    // 10) mask scatter
    k_mask<<<(NB + TPB - 1) / TPB, TPB, 0, stream>>>(batch, mask);

    // 11) layer-2 aggregation + final fuse + l2norm -> out_entity
    k_node2<<<wave_blocks_40000, TPB, 0, stream>>>(rowptr, eidx, src_el, edge_type, nhop,
                                                   Qs, Qt, R2, w2, entW, mask, out);

    // 12) ortho scalar
    k_ortho<<<1, TPB, 0, stream>>>(att_a, out_a, out + 8094800);
}

// Round 2
// 957.762 us; speedup vs baseline: 1.1725x; 1.1725x over previous
//
#include <hip/hip_runtime.h>
#include <cstdint>
#include <cstddef>
#include <math.h>

#define N_NODES 40000
#define N_RELS  474
#define E0      100000   // edge_list edges
#define EN      30000    // nhop edges
#define NE      130000   // total
#define NB      8192     // batch rows
#define LRALPHA 0.2f

// ---------------- row L2 normalize (wave per row) ----------------
__global__ void k_l2norm(const float* __restrict__ in, float* __restrict__ out, int M, int F) {
    int w = (blockIdx.x * blockDim.x + threadIdx.x) >> 6;
    int lane = threadIdx.x & 63;
    if (w >= M) return;
    const float* r = in + (size_t)w * F;
    float ss = 0.f;
    for (int j = lane; j < F; j += 64) { float v = r[j]; ss += v * v; }
#pragma unroll
    for (int o = 32; o > 0; o >>= 1) ss += __shfl_down(ss, o);
    ss = __shfl(ss, 0);
    float inv = 1.f / fmaxf(sqrtf(ss), 1e-12f);
    float* dst = out + (size_t)w * F;
    for (int j = lane; j < F; j += 64) dst[j] = r[j] * inv;
}

// ---------------- generic tiled fp32 matmul ----------------
// BT=true : C[m,n] = sum_k A[m*lda+k] * B[n*ldb+k]
// BT=false: C[m,n] = sum_k A[m*lda+k] * B[k*ldb+n]
template <bool BT>
__global__ __launch_bounds__(256) void k_mm(const float* __restrict__ A, int lda,
                                            const float* __restrict__ B, int ldb,
                                            float* __restrict__ C, int ldc,
                                            int M, int N, int K) {
    __shared__ float As[16][65];
    __shared__ float Bs[16][65];
    int tid = threadIdx.x;
    int tx = tid & 15, ty = tid >> 4;
    int m0 = blockIdx.y * 64, n0 = blockIdx.x * 64;
    float acc[4][4] = {};
    for (int k0 = 0; k0 < K; k0 += 16) {
        {   // A tile: 64 rows x 16 k
            int r = tid >> 2;
            int c4 = (tid & 3) * 4;
            int m = m0 + r;
#pragma unroll
            for (int u = 0; u < 4; u++) {
                int k = k0 + c4 + u;
                As[c4 + u][r] = (m < M && k < K) ? A[(size_t)m * lda + k] : 0.f;
            }
        }
        if (BT) {
            int r = tid >> 2;
            int c4 = (tid & 3) * 4;
            int n = n0 + r;
#pragma unroll
            for (int u = 0; u < 4; u++) {
                int k = k0 + c4 + u;
                Bs[c4 + u][r] = (n < N && k < K) ? B[(size_t)n * ldb + k] : 0.f;
            }
        } else {
            int kk = tid >> 4;
            int nn4 = (tid & 15) * 4;
            int k = k0 + kk;
#pragma unroll
            for (int u = 0; u < 4; u++) {
                int n = n0 + nn4 + u;
                Bs[kk][nn4 + u] = (k < K && n < N) ? B[(size_t)k * ldb + n] : 0.f;
            }
        }
        __syncthreads();
#pragma unroll
        for (int k = 0; k < 16; k++) {
            float a[4], b[4];
#pragma unroll
            for (int i = 0; i < 4; i++) a[i] = As[k][ty + 16 * i];
#pragma unroll
            for (int j = 0; j < 4; j++) b[j] = Bs[k][tx + 16 * j];
#pragma unroll
            for (int i = 0; i < 4; i++)
#pragma unroll
                for (int j = 0; j < 4; j++) acc[i][j] += a[i] * b[j];
        }
        __syncthreads();
    }
#pragma unroll
    for (int i = 0; i < 4; i++) {
        int m = m0 + ty + 16 * i;
        if (m >= M) continue;
#pragma unroll
        for (int j = 0; j < 4; j++) {
            int n = n0 + tx + 16 * j;
            if (n < N) C[(size_t)m * ldc + n] = acc[i][j];
        }
    }
}

// ---------------- per-row dot with vector (wave per row) ----------------
__global__ void k_dotv(const float* __restrict__ mat, const float* __restrict__ vec,
                       float* __restrict__ out, int M, int F) {
    int w = (blockIdx.x * blockDim.x + threadIdx.x) >> 6;
    int lane = threadIdx.x & 63;
    if (w >= M) return;
    const float* r = mat + (size_t)w * F;
    float s = 0.f;
    for (int j = lane; j < F; j += 64) s += r[j] * vec[j];
#pragma unroll
    for (int o = 32; o > 0; o >>= 1) s += __shfl_down(s, o);
    if (lane == 0) out[w] = s;
}

// ---------------- CSR build ----------------
__global__ void k_hist(const int* __restrict__ tgt_el, const int* __restrict__ nhop,
                       int* __restrict__ deg) {
    int e = blockIdx.x * blockDim.x + threadIdx.x;
    if (e >= NE) return;
    int t = (e < E0) ? tgt_el[e] : nhop[(size_t)(e - E0) * 4 + 3];
    atomicAdd(&deg[t], 1);
}

// hierarchical scan: stage 1 — per-block exclusive scan + block sums
__global__ void k_scan1(const int* __restrict__ deg, int* __restrict__ local,
                        int* __restrict__ bsums, int n) {
    int i = blockIdx.x * 256 + threadIdx.x;
    int v = (i < n) ? deg[i] : 0;
    int lane = threadIdx.x & 63;
    int wv = threadIdx.x >> 6;
    int x = v;
#pragma unroll
    for (int o = 1; o < 64; o <<= 1) {
        int t = __shfl_up(x, o);
        if (lane >= o) x += t;
    }
    __shared__ int wtot[4];
    if (lane == 63) wtot[wv] = x;
    __syncthreads();
    int add = 0;
    for (int k = 0; k < wv; k++) add += wtot[k];
    if (i < n) local[i] = add + x - v;   // block-local exclusive
    if (threadIdx.x == 255) bsums[blockIdx.x] = add + x;  // block total
}

// stage 2 — single-block exclusive scan of block sums (nb <= 256)
__global__ void k_scan2(int* __restrict__ bsums, int nb) {
    int tid = threadIdx.x;
    int v = (tid < nb) ? bsums[tid] : 0;
    int lane = tid & 63, wv = tid >> 6;
    int x = v;
#pragma unroll
    for (int o = 1; o < 64; o <<= 1) {
        int t = __shfl_up(x, o);
        if (lane >= o) x += t;
    }
    __shared__ int wtot[4];
    if (lane == 63) wtot[wv] = x;
    __syncthreads();
    int add = 0;
    for (int k = 0; k < wv; k++) add += wtot[k];
    __syncthreads();   // everyone read bsums before overwrite
    if (tid < nb) bsums[tid] = add + x - v;   // exclusive
    if (tid == 255) bsums[nb] = add + x;      // grand total
}

// stage 3 — add block offsets, write rowptr + cursor
__global__ void k_scan3(const int* __restrict__ local, const int* __restrict__ bsums,
                        int* __restrict__ rowptr, int* __restrict__ cursor, int n, int nb) {
    int i = blockIdx.x * 256 + threadIdx.x;
    if (i < n) {
        int v = local[i] + bsums[blockIdx.x];
        rowptr[i] = v;
        cursor[i] = v;
    } else if (i == n) {
        rowptr[n] = bsums[nb];
    }
}

__global__ void k_scatter(const int* __restrict__ tgt_el, const int* __restrict__ nhop,
                          int* __restrict__ cursor, int* __restrict__ eidx) {
    int e = blockIdx.x * blockDim.x + threadIdx.x;
    if (e >= NE) return;
    int t = (e < E0) ? tgt_el[e] : nhop[(size_t)(e - E0) * 4 + 3];
    int p = atomicAdd(&cursor[t], 1);
    eidx[p] = e;
}

// ---------------- per-edge attention scalar, layer 1 (both heads) ----------------
__global__ void k_edge1(const int* __restrict__ tgt_el, const int* __restrict__ src_el,
                        const int* __restrict__ etype, const int* __restrict__ nhop,
                        const float* __restrict__ dpt0, const float* __restrict__ dps0,
                        const float* __restrict__ dR0,
                        const float* __restrict__ dpt1, const float* __restrict__ dps1,
                        const float* __restrict__ dR1,
                        float* __restrict__ w0, float* __restrict__ w1) {
    int e = blockIdx.x * blockDim.x + threadIdx.x;
    if (e >= NE) return;
    int t, s; float dr0, dr1;
    if (e < E0) {
        t = tgt_el[e]; s = src_el[e];
        int r = etype[e];
        dr0 = dR0[r]; dr1 = dR1[r];
    } else {
        const int* nh = nhop + (size_t)(e - E0) * 4;
        t = nh[3]; s = nh[0];
        dr0 = dR0[nh[1]] + dR0[nh[2]];
        dr1 = dR1[nh[1]] + dR1[nh[2]];
    }
    float p0 = dpt0[t] + dps0[s] + dr0;
    float p1 = dpt1[t] + dps1[s] + dr1;
    p0 = (p0 >= 0.f) ? p0 : LRALPHA * p0;
    p1 = (p1 >= 0.f) ? p1 : LRALPHA * p1;
    w0[e] = expf(-p0);
    w1[e] = expf(-p1);
}

// ---------------- per-edge attention scalar, layer 2 ----------------
__global__ void k_edge2(const int* __restrict__ tgt_el, const int* __restrict__ src_el,
                        const int* __restrict__ etype, const int* __restrict__ nhop,
                        const float* __restrict__ dqt, const float* __restrict__ dqs,
                        const float* __restrict__ dR2, float* __restrict__ w2) {
    int e = blockIdx.x * blockDim.x + threadIdx.x;
    if (e >= NE) return;
    int t, s; float dr;
    if (e < E0) {
        t = tgt_el[e]; s = src_el[e];
        dr = dR2[etype[e]];
    } else {
        const int* nh = nhop + (size_t)(e - E0) * 4;
        t = nh[3]; s = nh[0];
        dr = dR2[nh[1]] + dR2[nh[2]];
    }
    float p = dqt[t] + dqs[s] + dr;
    p = (p >= 0.f) ? p : LRALPHA * p;
    w2[e] = expf(-p);
}

// ---------------- node aggregation layer 1, both heads fused (wave/node) ----------------
__global__ void k_node1(const int* __restrict__ rowptr, const int* __restrict__ eidx,
                        const int* __restrict__ src_el, const int* __restrict__ etype,
                        const int* __restrict__ nhop,
                        const float* __restrict__ Ps0, const float* __restrict__ Ps1,
                        const float* __restrict__ Pt0, const float* __restrict__ Pt1,
                        const float* __restrict__ R10, const float* __restrict__ R11,
                        const float* __restrict__ w0, const float* __restrict__ w1,
                        float* __restrict__ x) {
    int node = (blockIdx.x * blockDim.x + threadIdx.x) >> 6;
    int lane = threadIdx.x & 63;
    if (node >= N_NODES) return;
    int j1 = lane + 64;
    bool v1 = (j1 < 100);
    float a00 = 0, a01 = 0, a10 = 0, a11 = 0, rs0 = 0, rs1 = 0;
    int beg = rowptr[node], end = rowptr[node + 1];
    for (int p = beg; p < end; p++) {
        int e = eidx[p];
        int s; float r00, r01, r10, r11;
        if (e < E0) {
            s = src_el[e];
            int t = etype[e];
            const float* q0 = R10 + (size_t)t * 100;
            const float* q1 = R11 + (size_t)t * 100;
            r00 = q0[lane]; r01 = v1 ? q0[j1] : 0.f;
            r10 = q1[lane]; r11 = v1 ? q1[j1] : 0.f;
        } else {
            const int* nh = nhop + (size_t)(e - E0) * 4;
            s = nh[0];
            const float* q0a = R10 + (size_t)nh[1] * 100;
            const float* q0b = R10 + (size_t)nh[2] * 100;
            const float* q1a = R11 + (size_t)nh[1] * 100;
            const float* q1b = R11 + (size_t)nh[2] * 100;
            r00 = q0a[lane] + q0b[lane]; r01 = v1 ? (q0a[j1] + q0b[j1]) : 0.f;
            r10 = q1a[lane] + q1b[lane]; r11 = v1 ? (q1a[j1] + q1b[j1]) : 0.f;
        }
        float W0 = w0[e], W1 = w1[e];
        rs0 += W0; rs1 += W1;
        const float* ps0 = Ps0 + (size_t)s * 100;
        const float* ps1 = Ps1 + (size_t)s * 100;
        a00 += W0 * (ps0[lane] + r00);
        a10 += W1 * (ps1[lane] + r10);
        if (v1) {
            a01 += W0 * (ps0[j1] + r01);
            a11 += W1 * (ps1[j1] + r11);
        }
    }
    float d0 = (rs0 == 0.f) ? 1e-12f : rs0;
    float d1 = (rs1 == 0.f) ? 1e-12f : rs1;
    const float* pt0 = Pt0 + (size_t)node * 100;
    const float* pt1 = Pt1 + (size_t)node * 100;
    float* xr = x + (size_t)node * 200;
    float v = (a00 + rs0 * pt0[lane]) / d0;
    xr[lane] = (v > 0.f) ? v : expm1f(v);
    float u = (a10 + rs1 * pt1[lane]) / d1;
    xr[100 + lane] = (u > 0.f) ? u : expm1f(u);
    if (v1) {
        float v2 = (a01 + rs0 * pt0[j1]) / d0;
        xr[j1] = (v2 > 0.f) ? v2 : expm1f(v2);
        float u2 = (a11 + rs1 * pt1[j1]) / d1;
        xr[100 + j1] = (u2 > 0.f) ? u2 : expm1f(u2);
    }
}

// ---------------- node aggregation layer 2 + final fuse (wave/node) ----------------
__global__ void k_node2(const int* __restrict__ rowptr, const int* __restrict__ eidx,
                        const int* __restrict__ src_el, const int* __restrict__ etype,
                        const int* __restrict__ nhop,
                        const float* __restrict__ Qs, const float* __restrict__ Qt,
                        const float* __restrict__ R2, const float* __restrict__ w2,
                        const float* __restrict__ entW, const float* __restrict__ mask,
                        float* __restrict__ out) {
    int node = (blockIdx.x * blockDim.x + threadIdx.x) >> 6;
    int lane = threadIdx.x & 63;
    if (node >= N_NODES) return;
    bool v3 = (lane < 8);
    int j3 = lane + 192;
    float acc0 = 0, acc1 = 0, acc2 = 0, acc3 = 0, rs = 0;
    int beg = rowptr[node], end = rowptr[node + 1];
    for (int p = beg; p < end; p++) {
        int e = eidx[p];
        int s; const float* ra; const float* rb = nullptr;
        if (e < E0) {
            s = src_el[e];
            ra = R2 + (size_t)etype[e] * 200;
        } else {
            const int* nh = nhop + (size_t)(e - E0) * 4;
            s = nh[0];
            ra = R2 + (size_t)nh[1] * 200;
            rb = R2 + (size_t)nh[2] * 200;
        }
        float W = w2[e]; rs += W;
        const float* qs = Qs + (size_t)s * 200;
        float r0 = ra[lane], r1 = ra[lane + 64], r2 = ra[lane + 128];
        float r3 = v3 ? ra[j3] : 0.f;
        if (rb) {
            r0 += rb[lane]; r1 += rb[lane + 64]; r2 += rb[lane + 128];
            if (v3) r3 += rb[j3];
        }
        acc0 += W * (qs[lane] + r0);
        acc1 += W * (qs[lane + 64] + r1);
        acc2 += W * (qs[lane + 128] + r2);
        if (v3) acc3 += W * (qs[j3] + r3);
    }
    float d = (rs == 0.f) ? 1e-12f : rs;
    const float* qt = Qt + (size_t)node * 200;
    const float* ew = entW + (size_t)node * 200;
    float mk = mask[node];
    float val0 = ew[lane]       + mk * ((acc0 + rs * qt[lane]) / d);
    float val1 = ew[lane + 64]  + mk * ((acc1 + rs * qt[lane + 64]) / d);
    float val2 = ew[lane + 128] + mk * ((acc2 + rs * qt[lane + 128]) / d);
    float val3 = v3 ? (ew[j3] + mk * ((acc3 + rs * qt[j3]) / d)) : 0.f;
    float ss = val0 * val0 + val1 * val1 + val2 * val2 + val3 * val3;
#pragma unroll
    for (int o = 32; o > 0; o >>= 1) ss += __shfl_down(ss, o);
    ss = __shfl(ss, 0);
    float inv = 1.f / fmaxf(sqrtf(ss), 1e-12f);
    float* dst = out + (size_t)node * 200;
    dst[lane] = val0 * inv;
    dst[lane + 64] = val1 * inv;
    dst[lane + 128] = val2 * inv;
    if (v3) dst[j3] = val3 * inv;
}

// ---------------- mask scatter ----------------
__global__ void k_mask(const int* __restrict__ batch, float* __restrict__ mask) {
    int i = blockIdx.x * blockDim.x + threadIdx.x;
    if (i < NB) mask[batch[(size_t)i * 3 + 2]] = 1.0f;
}

// ---------------- ortho losses (single block) ----------------
__global__ void k_ortho(const float* __restrict__ att_a, const float* __restrict__ out_a,
                        float* __restrict__ out_scalar) {
    __shared__ float r0[4], r1[4], rc[4];
    int tid = threadIdx.x, lane = tid & 63, wv = tid >> 6;
    float total = 0.f;
    for (int m = 0; m < 3; m++) {
        const float* base; int L;
        if (m == 0)      { base = att_a;          L = 15000; }
        else if (m == 1) { base = att_a + 30000;  L = 15000; }
        else             { base = out_a;          L = 60000; }
        float s0 = 0.f, s1 = 0.f, sc = 0.f;
        for (int i = tid; i < L; i += 256) {
            float a = base[i], b = base[L + i];
            s0 += a * a; s1 += b * b; sc += a * b;
        }
#pragma unroll
        for (int o = 32; o > 0; o >>= 1) {
            s0 += __shfl_down(s0, o);
            s1 += __shfl_down(s1, o);
            sc += __shfl_down(sc, o);
        }
        if (lane == 0) { r0[wv] = s0; r1[wv] = s1; rc[wv] = sc; }
        __syncthreads();
        if (tid == 0) {
            float t0 = 0, t1 = 0, tc = 0;
            for (int k = 0; k < 4; k++) { t0 += r0[k]; t1 += r1[k]; tc += rc[k]; }
            float c = tc / (fmaxf(sqrtf(t0), 1e-12f) * fmaxf(sqrtf(t1), 1e-12f));
            total += 0.01f * 2.f * c * c;   // lambda * (2 off-diagonal c^2); diagonal terms are 0
        }
        __syncthreads();
    }
    if (tid == 0) out_scalar[0] = total;
}

// ---------------- launch ----------------
extern "C" void kernel_launch(void* const* d_in, const int* in_sizes, int n_in,
                              void* d_out, int out_size, void* d_ws, size_t ws_size,
                              hipStream_t stream) {
    const int* edge_list = (const int*)d_in[0];   // [2][E0]
    const int* edge_type = (const int*)d_in[1];   // [E0]
    const int* batch     = (const int*)d_in[2];   // [NB][3]
    const int* nhop      = (const int*)d_in[3];   // [EN][4]
    const float* ent_emb = (const float*)d_in[4]; // [40000][100]
    const float* rel_emb = (const float*)d_in[5]; // [474][100]
    const float* W_ent   = (const float*)d_in[6]; // [100][200]
    const float* W_rel   = (const float*)d_in[7]; // [100][200]
    const float* att_a   = (const float*)d_in[8]; // [2][100][300]
    const float* att_a2  = (const float*)d_in[9]; // [2][100]
    const float* out_a   = (const float*)d_in[10];// [200][600]
    const float* out_a2  = (const float*)d_in[11];// [200]
    float* out = (float*)d_out;
    const int* tgt_el = edge_list;
    const int* src_el = edge_list + E0;

    // workspace carve-up (256B aligned)
    char* ws = (char*)d_ws;
    size_t o = 0;
    auto alloc = [&](size_t nbytes) -> char* {
        char* p = ws + o;
        o += (nbytes + 255) & ~(size_t)255;
        return p;
    };
    float* ent  = (float*)alloc(40000u * 100 * 4);
    float* Pt0  = (float*)alloc(40000u * 100 * 4);  // layer2: Qt spans Pt0+Ps0
    float* Ps0  = (float*)alloc(40000u * 100 * 4);
    float* Pt1  = (float*)alloc(40000u * 100 * 4);  // layer2: Qs spans Pt1+Ps1
    float* Ps1  = (float*)alloc(40000u * 100 * 4);
    float* xbuf = (float*)alloc(40000u * 200 * 4);  // x, then entW
    float* R10  = (float*)alloc(474u * 100 * 4);
    float* R11  = (float*)alloc(474u * 100 * 4);
    float* R2   = (float*)alloc(474u * 200 * 4);
    float* dpt0 = (float*)alloc(40000u * 4);
    float* dps0 = (float*)alloc(40000u * 4);
    float* dpt1 = (float*)alloc(40000u * 4);
    float* dps1 = (float*)alloc(40000u * 4);
    float* dqt  = (float*)alloc(40000u * 4);
    float* dqs  = (float*)alloc(40000u * 4);
    float* dR10 = (float*)alloc(474u * 4);
    float* dR11 = (float*)alloc(474u * 4);
    float* dR2  = (float*)alloc(474u * 4);
    float* w0   = (float*)alloc((size_t)NE * 4);
    float* w1   = (float*)alloc((size_t)NE * 4);
    float* w2   = (float*)alloc((size_t)NE * 4);
    int* rowptr = (int*)alloc((N_NODES + 1) * 4);
    int* cursor = (int*)alloc(N_NODES * 4);
    int* eidx   = (int*)alloc((size_t)NE * 4);
    float* mask = (float*)alloc(N_NODES * 4);
    int* scanloc = (int*)alloc(N_NODES * 4);
    int* bsums   = (int*)alloc(260 * 4);
    float* Qt = Pt0;      // 40000x200 reuse (layer-1 P dead by then)
    float* Qs = Pt1;
    float* entW = xbuf;   // overwrite x after Qt/Qs matmuls

    const int TPB = 256;
    int wave_blocks_40000 = (N_NODES * 64 + TPB - 1) / TPB;   // 10000
    int wave_blocks_474   = (N_RELS * 64 + TPB - 1) / TPB;    // 119
    int edge_blocks       = (NE + TPB - 1) / TPB;
    int scan_blocks       = (N_NODES + 255) / 256;            // 157

    // zero deg (cursor) and mask
    hipMemsetAsync(cursor, 0, N_NODES * 4, stream);
    hipMemsetAsync(mask, 0, N_NODES * 4, stream);

    // 1) normalize entities
    k_l2norm<<<wave_blocks_40000, TPB, 0, stream>>>(ent_emb, ent, N_NODES, 100);

    // 2) CSR by target (shared by all 3 aggregation passes) — hierarchical scan
    k_hist<<<edge_blocks, TPB, 0, stream>>>(tgt_el, nhop, cursor);
    k_scan1<<<scan_blocks, 256, 0, stream>>>(cursor, scanloc, bsums, N_NODES);
    k_scan2<<<1, 256, 0, stream>>>(bsums, scan_blocks);
    k_scan3<<<(N_NODES + 1 + 255) / 256, 256, 0, stream>>>(scanloc, bsums, rowptr, cursor, N_NODES, scan_blocks);
    k_scatter<<<edge_blocks, TPB, 0, stream>>>(tgt_el, nhop, cursor, eidx);

    // 3) layer-1 projections: P = ent @ a_part^T, R = rel_emb @ a_r^T
    dim3 g1((100 + 63) / 64, (N_NODES + 63) / 64);
    k_mm<true><<<g1, TPB, 0, stream>>>(ent, 100, att_a + 0,     300, Pt0, 100, N_NODES, 100, 100);
    k_mm<true><<<g1, TPB, 0, stream>>>(ent, 100, att_a + 100,   300, Ps0, 100, N_NODES, 100, 100);
    k_mm<true><<<g1, TPB, 0, stream>>>(ent, 100, att_a + 30000, 300, Pt1, 100, N_NODES, 100, 100);
    k_mm<true><<<g1, TPB, 0, stream>>>(ent, 100, att_a + 30100, 300, Ps1, 100, N_NODES, 100, 100);
    dim3 gr1((100 + 63) / 64, (N_RELS + 63) / 64);
    k_mm<true><<<gr1, TPB, 0, stream>>>(rel_emb, 100, att_a + 200,   300, R10, 100, N_RELS, 100, 100);
    k_mm<true><<<gr1, TPB, 0, stream>>>(rel_emb, 100, att_a + 30200, 300, R11, 100, N_RELS, 100, 100);

    // 4) logit decompositions
    k_dotv<<<wave_blocks_40000, TPB, 0, stream>>>(Pt0, att_a2,       dpt0, N_NODES, 100);
    k_dotv<<<wave_blocks_40000, TPB, 0, stream>>>(Ps0, att_a2,       dps0, N_NODES, 100);
    k_dotv<<<wave_blocks_40000, TPB, 0, stream>>>(Pt1, att_a2 + 100, dpt1, N_NODES, 100);
    k_dotv<<<wave_blocks_40000, TPB, 0, stream>>>(Ps1, att_a2 + 100, dps1, N_NODES, 100);
    k_dotv<<<wave_blocks_474, TPB, 0, stream>>>(R10, att_a2,       dR10, N_RELS, 100);
    k_dotv<<<wave_blocks_474, TPB, 0, stream>>>(R11, att_a2 + 100, dR11, N_RELS, 100);

    // 5) per-edge weights, layer 1 (both heads)
    k_edge1<<<edge_blocks, TPB, 0, stream>>>(tgt_el, src_el, edge_type, nhop,
                                             dpt0, dps0, dR10, dpt1, dps1, dR11, w0, w1);

    // 6) layer-1 aggregation -> x (40000x200)
    k_node1<<<wave_blocks_40000, TPB, 0, stream>>>(rowptr, eidx, src_el, edge_type, nhop,
                                                   Ps0, Ps1, Pt0, Pt1, R10, R11, w0, w1, xbuf);

    // 7) layer-2 projections
    dim3 g2((200 + 63) / 64, (N_NODES + 63) / 64);
    k_mm<true><<<g2, TPB, 0, stream>>>(xbuf, 200, out_a + 0,   600, Qt, 200, N_NODES, 200, 200);
    k_mm<true><<<g2, TPB, 0, stream>>>(xbuf, 200, out_a + 200, 600, Qs, 200, N_NODES, 200, 200);
    // out_relation_1 = rel_emb @ W_rel  -> directly into d_out
    dim3 gor((200 + 63) / 64, (N_RELS + 63) / 64);
    k_mm<false><<<gor, TPB, 0, stream>>>(rel_emb, 100, W_rel, 200, out + 8000000, 200, N_RELS, 200, 100);
    k_mm<true><<<gor, TPB, 0, stream>>>(out + 8000000, 200, out_a + 400, 600, R2, 200, N_RELS, 200, 200);
    k_dotv<<<wave_blocks_40000, TPB, 0, stream>>>(Qt, out_a2, dqt, N_NODES, 200);
    k_dotv<<<wave_blocks_40000, TPB, 0, stream>>>(Qs, out_a2, dqs, N_NODES, 200);
    k_dotv<<<wave_blocks_474, TPB, 0, stream>>>(R2, out_a2, dR2, N_RELS, 200);

    // 8) per-edge weights, layer 2
    k_edge2<<<edge_blocks, TPB, 0, stream>>>(tgt_el, src_el, edge_type, nhop, dqt, dqs, dR2, w2);

    // 9) entW = ent @ W_entities (overwrites xbuf; x no longer needed)
    k_mm<false><<<g2, TPB, 0, stream>>>(ent, 100, W_ent, 200, entW, 200, N_NODES, 200, 100);

    // 10) mask scatter
    k_mask<<<(NB + TPB - 1) / TPB, TPB, 0, stream>>>(batch, mask);

    // 11) layer-2 aggregation + final fuse + l2norm -> out_entity
    k_node2<<<wave_blocks_40000, TPB, 0, stream>>>(rowptr, eidx, src_el, edge_type, nhop,
                                                   Qs, Qt, R2, w2, entW, mask, out);

    // 12) ortho scalar
    k_ortho<<<1, TPB, 0, stream>>>(att_a, out_a, out + 8094800);
}

// Round 3
// 658.912 us; speedup vs baseline: 1.7043x; 1.4536x over previous
//
#include <hip/hip_runtime.h>
#include <cstdint>
#include <cstddef>
#include <math.h>

#define N_NODES 40000
#define N_RELS  474
#define E0      100000
#define EN      30000
#define NE      130000
#define NB      8192
#define LRALPHA 0.2f

#define KP1 128   // padded K for layer-1 GEMM (K=100)
#define KP2 256   // padded K for layer-2 GEMM (K=200)
#define LD1 608   // Pcat row stride: [Pt0|Ps0|Pt1|Ps1|entW(200)|dots(4)|pad(4)]
#define LD2 416   // Qcat row stride: [Qt(200)|Qs(200)|dqt|dqs|pad(14)]

typedef __attribute__((ext_vector_type(8))) short short8;
typedef __attribute__((ext_vector_type(4))) float floatx4;

static __device__ __forceinline__ unsigned short f2bf(float f) {
    union { float f; uint32_t u; } v; v.f = f;
    uint32_t r = v.u + 0x7fff + ((v.u >> 16) & 1);
    return (unsigned short)(r >> 16);
}
static __device__ __forceinline__ float bf2f(unsigned short h) {
    union { uint32_t u; float f; } v; v.u = ((uint32_t)h) << 16;
    return v.f;
}

// ---------------- l2norm rows of ent -> bf16 padded [40000][KP1] ----------------
__global__ void k_l2norm_bf16(const float* __restrict__ in, unsigned short* __restrict__ out) {
    int w = (blockIdx.x * blockDim.x + threadIdx.x) >> 6;
    int lane = threadIdx.x & 63;
    if (w >= N_NODES) return;
    const float* r = in + (size_t)w * 100;
    float v0 = r[lane];
    int j1 = lane + 64;
    float v1 = (j1 < 100) ? r[j1] : 0.f;
    float ss = v0 * v0 + v1 * v1;
#pragma unroll
    for (int o = 32; o > 0; o >>= 1) ss += __shfl_down(ss, o);
    ss = __shfl(ss, 0);
    float inv = 1.f / fmaxf(sqrtf(ss), 1e-12f);
    unsigned short* dst = out + (size_t)w * KP1;
    dst[lane] = f2bf(v0 * inv);
    dst[j1] = (j1 < 100) ? f2bf(v1 * inv) : (unsigned short)0;
}

// ---------------- bf16 MFMA GEMM: C[m][n] = sum_k A[m][k] * B[n][k] ----------------
// A: [M][KP] bf16 row-major (M mult of 64), B: [N][KP] bf16 row-major (N mult of 16)
// C: [M][ldc] bf16. grid: (M/64, ceil(N/128)), block 256.
template <int KP>
__global__ __launch_bounds__(256) void k_gemm_mfma(const unsigned short* __restrict__ A,
                                                   const unsigned short* __restrict__ B,
                                                   unsigned short* __restrict__ C,
                                                   int ldc, int N) {
    constexpr int KSTEPS = KP / 32;
    int wave = threadIdx.x >> 6;
    int lane = threadIdx.x & 63;
    int quad = lane >> 4;
    int l16 = lane & 15;
    int m0 = blockIdx.x * 64 + wave * 16;
    int n_base = blockIdx.y * 128;
    // load this wave's 16-row A strip (full K) into registers
    short8 afrag[KSTEPS];
    const unsigned short* arow = A + (size_t)(m0 + l16) * KP + quad * 8;
#pragma unroll
    for (int ks = 0; ks < KSTEPS; ks++)
        afrag[ks] = *(const short8*)(arow + ks * 32);
    int ntiles = (N - n_base) >> 4;
    if (ntiles > 8) ntiles = 8;
    for (int t = 0; t < ntiles; t++) {
        int n0 = n_base + t * 16;
        const unsigned short* brow = B + (size_t)(n0 + l16) * KP + quad * 8;
        floatx4 acc = {0.f, 0.f, 0.f, 0.f};
#pragma unroll
        for (int ks = 0; ks < KSTEPS; ks++) {
            short8 bfrag = *(const short8*)(brow + ks * 32);
            acc = __builtin_amdgcn_mfma_f32_16x16x32_bf16(afrag[ks], bfrag, acc, 0, 0, 0);
        }
        // C/D layout: col = lane&15, row = quad*4 + reg
        unsigned short* cp = C + (size_t)(m0 + quad * 4) * ldc + n0 + l16;
        cp[0] = f2bf(acc[0]);
        cp[(size_t)ldc] = f2bf(acc[1]);
        cp[(size_t)2 * ldc] = f2bf(acc[2]);
        cp[(size_t)3 * ldc] = f2bf(acc[3]);
    }
}

// ---------------- u-vectors: u = a_part^T @ a2 ----------------
// uvecs layout: [0:100)=u_t0 [100:200)=u_s0 [200:300)=u_t1 [300:400)=u_s1 [400:600)=u_t2 [600:800)=u_s2
__global__ void k_uvec(const float* __restrict__ att_a, const float* __restrict__ att_a2,
                       const float* __restrict__ out_a, const float* __restrict__ out_a2,
                       float* __restrict__ uvecs) {
    int tid = blockIdx.x * blockDim.x + threadIdx.x;
    if (tid >= 800) return;
    float s = 0.f;
    if (tid < 400) {
        int v = tid / 100, k = tid % 100;
        int head = v >> 1, part = v & 1;
        const float* base = att_a + head * 30000 + part * 100 + k;
        const float* a2 = att_a2 + head * 100;
        for (int n = 0; n < 100; n++) s += a2[n] * base[n * 300];
        uvecs[tid] = s;
    } else {
        int v = (tid - 400) / 200, k = (tid - 400) % 200;
        const float* base = out_a + v * 200 + k;
        for (int n = 0; n < 200; n++) s += out_a2[n] * base[n * 600];
        uvecs[400 + v * 200 + k] = s;
    }
}

// ---------------- pack layer-1 B matrix: Wcat1 [608][KP1] bf16 ----------------
__global__ void k_pack1(const float* __restrict__ att_a, const float* __restrict__ W_ent,
                        const float* __restrict__ uvecs, unsigned short* __restrict__ W) {
    int idx = blockIdx.x * blockDim.x + threadIdx.x;
    if (idx >= 608 * KP1) return;
    int r = idx >> 7, k = idx & (KP1 - 1);
    float val = 0.f;
    if (k < 100) {
        if (r < 100)       val = att_a[r * 300 + k];
        else if (r < 200)  val = att_a[(r - 100) * 300 + 100 + k];
        else if (r < 300)  val = att_a[30000 + (r - 200) * 300 + k];
        else if (r < 400)  val = att_a[30000 + (r - 300) * 300 + 100 + k];
        else if (r < 600)  val = W_ent[k * 200 + (r - 400)];
        else if (r < 604)  val = uvecs[(r - 600) * 100 + k];
    }
    W[idx] = f2bf(val);
}

// ---------------- pack layer-2 B matrix: Wcat2 [416][KP2] bf16 ----------------
__global__ void k_pack2(const float* __restrict__ out_a, const float* __restrict__ uvecs,
                        unsigned short* __restrict__ W) {
    int idx = blockIdx.x * blockDim.x + threadIdx.x;
    if (idx >= 416 * KP2) return;
    int r = idx >> 8, k = idx & (KP2 - 1);
    float val = 0.f;
    if (k < 200) {
        if (r < 200)       val = out_a[r * 600 + k];
        else if (r < 400)  val = out_a[(r - 200) * 600 + 200 + k];
        else if (r == 400) val = uvecs[400 + k];
        else if (r == 401) val = uvecs[600 + k];
    }
    W[idx] = f2bf(val);
}

// ---------------- generic tiled fp32 matmul (474-row cases only) ----------------
template <bool BT>
__global__ __launch_bounds__(256) void k_mm(const float* __restrict__ A, int lda,
                                            const float* __restrict__ B, int ldb,
                                            float* __restrict__ C, int ldc,
                                            int M, int N, int K) {
    __shared__ float As[16][65];
    __shared__ float Bs[16][65];
    int tid = threadIdx.x;
    int tx = tid & 15, ty = tid >> 4;
    int m0 = blockIdx.y * 64, n0 = blockIdx.x * 64;
    float acc[4][4] = {};
    for (int k0 = 0; k0 < K; k0 += 16) {
        {
            int r = tid >> 2;
            int c4 = (tid & 3) * 4;
            int m = m0 + r;
#pragma unroll
            for (int u = 0; u < 4; u++) {
                int k = k0 + c4 + u;
                As[c4 + u][r] = (m < M && k < K) ? A[(size_t)m * lda + k] : 0.f;
            }
        }
        if (BT) {
            int r = tid >> 2;
            int c4 = (tid & 3) * 4;
            int n = n0 + r;
#pragma unroll
            for (int u = 0; u < 4; u++) {
                int k = k0 + c4 + u;
                Bs[c4 + u][r] = (n < N && k < K) ? B[(size_t)n * ldb + k] : 0.f;
            }
        } else {
            int kk = tid >> 4;
            int nn4 = (tid & 15) * 4;
            int k = k0 + kk;
#pragma unroll
            for (int u = 0; u < 4; u++) {
                int n = n0 + nn4 + u;
                Bs[kk][nn4 + u] = (k < K && n < N) ? B[(size_t)k * ldb + n] : 0.f;
            }
        }
        __syncthreads();
#pragma unroll
        for (int k = 0; k < 16; k++) {
            float a[4], b[4];
#pragma unroll
            for (int i = 0; i < 4; i++) a[i] = As[k][ty + 16 * i];
#pragma unroll
            for (int j = 0; j < 4; j++) b[j] = Bs[k][tx + 16 * j];
#pragma unroll
            for (int i = 0; i < 4; i++)
#pragma unroll
                for (int j = 0; j < 4; j++) acc[i][j] += a[i] * b[j];
        }
        __syncthreads();
    }
#pragma unroll
    for (int i = 0; i < 4; i++) {
        int m = m0 + ty + 16 * i;
        if (m >= M) continue;
#pragma unroll
        for (int j = 0; j < 4; j++) {
            int n = n0 + tx + 16 * j;
            if (n < N) C[(size_t)m * ldc + n] = acc[i][j];
        }
    }
}

// ---------------- per-row dot with vector (474-row cases) ----------------
__global__ void k_dotv(const float* __restrict__ mat, const float* __restrict__ vec,
                       float* __restrict__ out, int M, int F) {
    int w = (blockIdx.x * blockDim.x + threadIdx.x) >> 6;
    int lane = threadIdx.x & 63;
    if (w >= M) return;
    const float* r = mat + (size_t)w * F;
    float s = 0.f;
    for (int j = lane; j < F; j += 64) s += r[j] * vec[j];
#pragma unroll
    for (int o = 32; o > 0; o >>= 1) s += __shfl_down(s, o);
    if (lane == 0) out[w] = s;
}

// ---------------- CSR build ----------------
__global__ void k_hist(const int* __restrict__ tgt_el, const int* __restrict__ nhop,
                       int* __restrict__ deg) {
    int e = blockIdx.x * blockDim.x + threadIdx.x;
    if (e >= NE) return;
    int t = (e < E0) ? tgt_el[e] : nhop[(size_t)(e - E0) * 4 + 3];
    atomicAdd(&deg[t], 1);
}

__global__ void k_scan1(const int* __restrict__ deg, int* __restrict__ local,
                        int* __restrict__ bsums, int n) {
    int i = blockIdx.x * 256 + threadIdx.x;
    int v = (i < n) ? deg[i] : 0;
    int lane = threadIdx.x & 63;
    int wv = threadIdx.x >> 6;
    int x = v;
#pragma unroll
    for (int o = 1; o < 64; o <<= 1) {
        int t = __shfl_up(x, o);
        if (lane >= o) x += t;
    }
    __shared__ int wtot[4];
    if (lane == 63) wtot[wv] = x;
    __syncthreads();
    int add = 0;
    for (int k = 0; k < wv; k++) add += wtot[k];
    if (i < n) local[i] = add + x - v;
    if (threadIdx.x == 255) bsums[blockIdx.x] = add + x;
}

__global__ void k_scan2(int* __restrict__ bsums, int nb) {
    int tid = threadIdx.x;
    int v = (tid < nb) ? bsums[tid] : 0;
    int lane = tid & 63, wv = tid >> 6;
    int x = v;
#pragma unroll
    for (int o = 1; o < 64; o <<= 1) {
        int t = __shfl_up(x, o);
        if (lane >= o) x += t;
    }
    __shared__ int wtot[4];
    if (lane == 63) wtot[wv] = x;
    __syncthreads();
    int add = 0;
    for (int k = 0; k < wv; k++) add += wtot[k];
    __syncthreads();
    if (tid < nb) bsums[tid] = add + x - v;
    if (tid == 255) bsums[nb] = add + x;
}

__global__ void k_scan3(const int* __restrict__ local, const int* __restrict__ bsums,
                        int* __restrict__ rowptr, int* __restrict__ cursor, int n, int nb) {
    int i = blockIdx.x * 256 + threadIdx.x;
    if (i < n) {
        int v = local[i] + bsums[blockIdx.x];
        rowptr[i] = v;
        cursor[i] = v;
    } else if (i == n) {
        rowptr[n] = bsums[nb];
    }
}

__global__ void k_scatter(const int* __restrict__ tgt_el, const int* __restrict__ nhop,
                          int* __restrict__ cursor, int* __restrict__ eidx) {
    int e = blockIdx.x * blockDim.x + threadIdx.x;
    if (e >= NE) return;
    int t = (e < E0) ? tgt_el[e] : nhop[(size_t)(e - E0) * 4 + 3];
    int p = atomicAdd(&cursor[t], 1);
    eidx[p] = e;
}

// ---------------- per-edge attention scalar, layer 1 (dots from Pcat bf16 cols) ----------------
__global__ void k_edge1(const int* __restrict__ tgt_el, const int* __restrict__ src_el,
                        const int* __restrict__ etype, const int* __restrict__ nhop,
                        const unsigned short* __restrict__ Pcat,
                        const float* __restrict__ dR0, const float* __restrict__ dR1,
                        float* __restrict__ w0, float* __restrict__ w1) {
    int e = blockIdx.x * blockDim.x + threadIdx.x;
    if (e >= NE) return;
    int t, s; float dr0, dr1;
    if (e < E0) {
        t = tgt_el[e]; s = src_el[e];
        int r = etype[e];
        dr0 = dR0[r]; dr1 = dR1[r];
    } else {
        const int* nh = nhop + (size_t)(e - E0) * 4;
        t = nh[3]; s = nh[0];
        dr0 = dR0[nh[1]] + dR0[nh[2]];
        dr1 = dR1[nh[1]] + dR1[nh[2]];
    }
    const unsigned short* pt = Pcat + (size_t)t * LD1 + 600;
    const unsigned short* ps = Pcat + (size_t)s * LD1 + 600;
    float p0 = bf2f(pt[0]) + bf2f(ps[1]) + dr0;
    float p1 = bf2f(pt[2]) + bf2f(ps[3]) + dr1;
    p0 = (p0 >= 0.f) ? p0 : LRALPHA * p0;
    p1 = (p1 >= 0.f) ? p1 : LRALPHA * p1;
    w0[e] = expf(-p0);
    w1[e] = expf(-p1);
}

// ---------------- per-edge attention scalar, layer 2 ----------------
__global__ void k_edge2(const int* __restrict__ tgt_el, const int* __restrict__ src_el,
                        const int* __restrict__ etype, const int* __restrict__ nhop,
                        const unsigned short* __restrict__ Qcat,
                        const float* __restrict__ dR2, float* __restrict__ w2) {
    int e = blockIdx.x * blockDim.x + threadIdx.x;
    if (e >= NE) return;
    int t, s; float dr;
    if (e < E0) {
        t = tgt_el[e]; s = src_el[e];
        dr = dR2[etype[e]];
    } else {
        const int* nh = nhop + (size_t)(e - E0) * 4;
        t = nh[3]; s = nh[0];
        dr = dR2[nh[1]] + dR2[nh[2]];
    }
    float p = bf2f(Qcat[(size_t)t * LD2 + 400]) + bf2f(Qcat[(size_t)s * LD2 + 401]) + dr;
    p = (p >= 0.f) ? p : LRALPHA * p;
    w2[e] = expf(-p);
}

// ---------------- node aggregation layer 1 (wave/node) -> x_bf16 [40000][KP2] ----------------
__global__ void k_node1(const int* __restrict__ rowptr, const int* __restrict__ eidx,
                        const int* __restrict__ src_el, const int* __restrict__ etype,
                        const int* __restrict__ nhop,
                        const unsigned short* __restrict__ Pcat,
                        const float* __restrict__ R10, const float* __restrict__ R11,
                        const float* __restrict__ w0, const float* __restrict__ w1,
                        unsigned short* __restrict__ x) {
    int node = (blockIdx.x * blockDim.x + threadIdx.x) >> 6;
    int lane = threadIdx.x & 63;
    if (node >= N_NODES) return;
    int j1 = lane + 64;
    bool v1 = (j1 < 100);
    float a00 = 0, a01 = 0, a10 = 0, a11 = 0, rs0 = 0, rs1 = 0;
    int beg = rowptr[node], end = rowptr[node + 1];
    for (int p = beg; p < end; p++) {
        int e = eidx[p];
        int s; float r00, r01, r10, r11;
        if (e < E0) {
            s = src_el[e];
            int t = etype[e];
            const float* q0 = R10 + (size_t)t * 100;
            const float* q1 = R11 + (size_t)t * 100;
            r00 = q0[lane]; r01 = v1 ? q0[j1] : 0.f;
            r10 = q1[lane]; r11 = v1 ? q1[j1] : 0.f;
        } else {
            const int* nh = nhop + (size_t)(e - E0) * 4;
            s = nh[0];
            const float* q0a = R10 + (size_t)nh[1] * 100;
            const float* q0b = R10 + (size_t)nh[2] * 100;
            const float* q1a = R11 + (size_t)nh[1] * 100;
            const float* q1b = R11 + (size_t)nh[2] * 100;
            r00 = q0a[lane] + q0b[lane]; r01 = v1 ? (q0a[j1] + q0b[j1]) : 0.f;
            r10 = q1a[lane] + q1b[lane]; r11 = v1 ? (q1a[j1] + q1b[j1]) : 0.f;
        }
        float W0 = w0[e], W1 = w1[e];
        rs0 += W0; rs1 += W1;
        const unsigned short* prow = Pcat + (size_t)s * LD1;
        a00 += W0 * (bf2f(prow[100 + lane]) + r00);   // Ps0
        a10 += W1 * (bf2f(prow[300 + lane]) + r10);   // Ps1
        if (v1) {
            a01 += W0 * (bf2f(prow[100 + j1]) + r01);
            a11 += W1 * (bf2f(prow[300 + j1]) + r11);
        }
    }
    float d0 = (rs0 == 0.f) ? 1e-12f : rs0;
    float d1 = (rs1 == 0.f) ? 1e-12f : rs1;
    const unsigned short* pn = Pcat + (size_t)node * LD1;
    unsigned short* xr = x + (size_t)node * KP2;
    float v = (a00 + rs0 * bf2f(pn[lane])) / d0;          // Pt0
    xr[lane] = f2bf((v > 0.f) ? v : expm1f(v));
    float u = (a10 + rs1 * bf2f(pn[200 + lane])) / d1;    // Pt1
    xr[100 + lane] = f2bf((u > 0.f) ? u : expm1f(u));
    if (v1) {
        float v2 = (a01 + rs0 * bf2f(pn[j1])) / d0;
        xr[j1] = f2bf((v2 > 0.f) ? v2 : expm1f(v2));
        float u2 = (a11 + rs1 * bf2f(pn[200 + j1])) / d1;
        xr[100 + j1] = f2bf((u2 > 0.f) ? u2 : expm1f(u2));
    }
    if (lane < KP2 - 200) xr[200 + lane] = 0;   // zero pad cols 200..255
}

// ---------------- node aggregation layer 2 + final fuse (wave/node) ----------------
__global__ void k_node2(const int* __restrict__ rowptr, const int* __restrict__ eidx,
                        const int* __restrict__ src_el, const int* __restrict__ etype,
                        const int* __restrict__ nhop,
                        const unsigned short* __restrict__ Qcat,
                        const unsigned short* __restrict__ Pcat,   // entW at col 400
                        const float* __restrict__ R2, const float* __restrict__ w2,
                        const float* __restrict__ mask,
                        float* __restrict__ out) {
    int node = (blockIdx.x * blockDim.x + threadIdx.x) >> 6;
    int lane = threadIdx.x & 63;
    if (node >= N_NODES) return;
    bool v3 = (lane < 8);
    int j3 = lane + 192;
    float acc0 = 0, acc1 = 0, acc2 = 0, acc3 = 0, rs = 0;
    int beg = rowptr[node], end = rowptr[node + 1];
    for (int p = beg; p < end; p++) {
        int e = eidx[p];
        int s; const float* ra; const float* rb = nullptr;
        if (e < E0) {
            s = src_el[e];
            ra = R2 + (size_t)etype[e] * 200;
        } else {
            const int* nh = nhop + (size_t)(e - E0) * 4;
            s = nh[0];
            ra = R2 + (size_t)nh[1] * 200;
            rb = R2 + (size_t)nh[2] * 200;
        }
        float W = w2[e]; rs += W;
        const unsigned short* qs = Qcat + (size_t)s * LD2 + 200;   // Qs
        float r0 = ra[lane], r1 = ra[lane + 64], r2 = ra[lane + 128];
        float r3 = v3 ? ra[j3] : 0.f;
        if (rb) {
            r0 += rb[lane]; r1 += rb[lane + 64]; r2 += rb[lane + 128];
            if (v3) r3 += rb[j3];
        }
        acc0 += W * (bf2f(qs[lane]) + r0);
        acc1 += W * (bf2f(qs[lane + 64]) + r1);
        acc2 += W * (bf2f(qs[lane + 128]) + r2);
        if (v3) acc3 += W * (bf2f(qs[j3]) + r3);
    }
    float d = (rs == 0.f) ? 1e-12f : rs;
    const unsigned short* qt = Qcat + (size_t)node * LD2;          // Qt
    const unsigned short* ew = Pcat + (size_t)node * LD1 + 400;    // entW
    float mk = mask[node];
    float val0 = bf2f(ew[lane])       + mk * ((acc0 + rs * bf2f(qt[lane])) / d);
    float val1 = bf2f(ew[lane + 64])  + mk * ((acc1 + rs * bf2f(qt[lane + 64])) / d);
    float val2 = bf2f(ew[lane + 128]) + mk * ((acc2 + rs * bf2f(qt[lane + 128])) / d);
    float val3 = v3 ? (bf2f(ew[j3]) + mk * ((acc3 + rs * bf2f(qt[j3])) / d)) : 0.f;
    float ss = val0 * val0 + val1 * val1 + val2 * val2 + val3 * val3;
#pragma unroll
    for (int o = 32; o > 0; o >>= 1) ss += __shfl_down(ss, o);
    ss = __shfl(ss, 0);
    float inv = 1.f / fmaxf(sqrtf(ss), 1e-12f);
    float* dst = out + (size_t)node * 200;
    dst[lane] = val0 * inv;
    dst[lane + 64] = val1 * inv;
    dst[lane + 128] = val2 * inv;
    if (v3) dst[j3] = val3 * inv;
}

// ---------------- mask scatter ----------------
__global__ void k_mask(const int* __restrict__ batch, float* __restrict__ mask) {
    int i = blockIdx.x * blockDim.x + threadIdx.x;
    if (i < NB) mask[batch[(size_t)i * 3 + 2]] = 1.0f;
}

// ---------------- ortho losses (single block) ----------------
__global__ void k_ortho(const float* __restrict__ att_a, const float* __restrict__ out_a,
                        float* __restrict__ out_scalar) {
    __shared__ float r0[4], r1[4], rc[4];
    int tid = threadIdx.x, lane = tid & 63, wv = tid >> 6;
    float total = 0.f;
    for (int m = 0; m < 3; m++) {
        const float* base; int L;
        if (m == 0)      { base = att_a;          L = 15000; }
        else if (m == 1) { base = att_a + 30000;  L = 15000; }
        else             { base = out_a;          L = 60000; }
        float s0 = 0.f, s1 = 0.f, sc = 0.f;
        for (int i = tid; i < L; i += 256) {
            float a = base[i], b = base[L + i];
            s0 += a * a; s1 += b * b; sc += a * b;
        }
#pragma unroll
        for (int o = 32; o > 0; o >>= 1) {
            s0 += __shfl_down(s0, o);
            s1 += __shfl_down(s1, o);
            sc += __shfl_down(sc, o);
        }
        if (lane == 0) { r0[wv] = s0; r1[wv] = s1; rc[wv] = sc; }
        __syncthreads();
        if (tid == 0) {
            float t0 = 0, t1 = 0, tc = 0;
            for (int k = 0; k < 4; k++) { t0 += r0[k]; t1 += r1[k]; tc += rc[k]; }
            float c = tc / (fmaxf(sqrtf(t0), 1e-12f) * fmaxf(sqrtf(t1), 1e-12f));
            total += 0.01f * 2.f * c * c;
        }
        __syncthreads();
    }
    if (tid == 0) out_scalar[0] = total;
}

// ---------------- launch ----------------
extern "C" void kernel_launch(void* const* d_in, const int* in_sizes, int n_in,
                              void* d_out, int out_size, void* d_ws, size_t ws_size,
                              hipStream_t stream) {
    const int* edge_list = (const int*)d_in[0];
    const int* edge_type = (const int*)d_in[1];
    const int* batch     = (const int*)d_in[2];
    const int* nhop      = (const int*)d_in[3];
    const float* ent_emb = (const float*)d_in[4];
    const float* rel_emb = (const float*)d_in[5];
    const float* W_ent   = (const float*)d_in[6];
    const float* W_rel   = (const float*)d_in[7];
    const float* att_a   = (const float*)d_in[8];
    const float* att_a2  = (const float*)d_in[9];
    const float* out_a   = (const float*)d_in[10];
    const float* out_a2  = (const float*)d_in[11];
    float* out = (float*)d_out;
    const int* tgt_el = edge_list;
    const int* src_el = edge_list + E0;

    char* ws = (char*)d_ws;
    size_t o = 0;
    auto alloc = [&](size_t nbytes) -> char* {
        char* p = ws + o;
        o += (nbytes + 255) & ~(size_t)255;
        return p;
    };
    unsigned short* ent_bf  = (unsigned short*)alloc((size_t)N_NODES * KP1 * 2);  // 10.2 MB
    unsigned short* x_bf    = (unsigned short*)alloc((size_t)N_NODES * KP2 * 2);  // 20.5 MB
    unsigned short* Pcat    = (unsigned short*)alloc((size_t)N_NODES * LD1 * 2);  // 48.6 MB
    unsigned short* Qcat    = (unsigned short*)alloc((size_t)N_NODES * LD2 * 2);  // 33.3 MB
    unsigned short* Wcat1   = (unsigned short*)alloc((size_t)608 * KP1 * 2);
    unsigned short* Wcat2   = (unsigned short*)alloc((size_t)416 * KP2 * 2);
    float* uvecs = (float*)alloc(800 * 4);
    float* R10   = (float*)alloc(474u * 100 * 4);
    float* R11   = (float*)alloc(474u * 100 * 4);
    float* R2    = (float*)alloc(474u * 200 * 4);
    float* dR10  = (float*)alloc(474u * 4);
    float* dR11  = (float*)alloc(474u * 4);
    float* dR2   = (float*)alloc(474u * 4);
    float* w0    = (float*)alloc((size_t)NE * 4);
    float* w1    = (float*)alloc((size_t)NE * 4);
    float* w2    = (float*)alloc((size_t)NE * 4);
    int* rowptr  = (int*)alloc((N_NODES + 1) * 4);
    int* cursor  = (int*)alloc(N_NODES * 4);
    int* eidx    = (int*)alloc((size_t)NE * 4);
    float* mask  = (float*)alloc(N_NODES * 4);
    int* scanloc = (int*)alloc(N_NODES * 4);
    int* bsums   = (int*)alloc(260 * 4);

    const int TPB = 256;
    int wave_blocks_40000 = (N_NODES * 64 + TPB - 1) / TPB;   // 10000
    int wave_blocks_474   = (N_RELS * 64 + TPB - 1) / TPB;    // 119
    int edge_blocks       = (NE + TPB - 1) / TPB;
    int scan_blocks       = (N_NODES + 255) / 256;            // 157

    hipMemsetAsync(cursor, 0, N_NODES * 4, stream);
    hipMemsetAsync(mask, 0, N_NODES * 4, stream);

    // 1) normalize entities -> bf16 padded
    k_l2norm_bf16<<<wave_blocks_40000, TPB, 0, stream>>>(ent_emb, ent_bf);

    // 2) CSR by target
    k_hist<<<edge_blocks, TPB, 0, stream>>>(tgt_el, nhop, cursor);
    k_scan1<<<scan_blocks, 256, 0, stream>>>(cursor, scanloc, bsums, N_NODES);
    k_scan2<<<1, 256, 0, stream>>>(bsums, scan_blocks);
    k_scan3<<<(N_NODES + 1 + 255) / 256, 256, 0, stream>>>(scanloc, bsums, rowptr, cursor, N_NODES, scan_blocks);
    k_scatter<<<edge_blocks, TPB, 0, stream>>>(tgt_el, nhop, cursor, eidx);

    // 3) pack fused B matrices
    k_uvec<<<4, 256, 0, stream>>>(att_a, att_a2, out_a, out_a2, uvecs);
    k_pack1<<<(608 * KP1 + 255) / 256, 256, 0, stream>>>(att_a, W_ent, uvecs, Wcat1);
    k_pack2<<<(416 * KP2 + 255) / 256, 256, 0, stream>>>(out_a, uvecs, Wcat2);

    // 4) fused layer-1 GEMM: Pcat = ent @ [a_t0|a_s0|a_t1|a_s1|W_ent|u]^T  (MFMA bf16)
    k_gemm_mfma<KP1><<<dim3(625, 5), 256, 0, stream>>>(ent_bf, Wcat1, Pcat, LD1, 608);

    // 5) relation-side projections (fp32, tiny)
    dim3 gr1((100 + 63) / 64, (N_RELS + 63) / 64);
    k_mm<true><<<gr1, TPB, 0, stream>>>(rel_emb, 100, att_a + 200,   300, R10, 100, N_RELS, 100, 100);
    k_mm<true><<<gr1, TPB, 0, stream>>>(rel_emb, 100, att_a + 30200, 300, R11, 100, N_RELS, 100, 100);
    k_dotv<<<wave_blocks_474, TPB, 0, stream>>>(R10, att_a2,       dR10, N_RELS, 100);
    k_dotv<<<wave_blocks_474, TPB, 0, stream>>>(R11, att_a2 + 100, dR11, N_RELS, 100);

    // 6) layer-1 edge weights + aggregation -> x_bf16
    k_edge1<<<edge_blocks, TPB, 0, stream>>>(tgt_el, src_el, edge_type, nhop, Pcat, dR10, dR11, w0, w1);
    k_node1<<<wave_blocks_40000, TPB, 0, stream>>>(rowptr, eidx, src_el, edge_type, nhop,
                                                   Pcat, R10, R11, w0, w1, x_bf);

    // 7) fused layer-2 GEMM: Qcat = x @ [out_a_t|out_a_s|u]^T  (MFMA bf16)
    k_gemm_mfma<KP2><<<dim3(625, 4), 256, 0, stream>>>(x_bf, Wcat2, Qcat, LD2, 416);

    // 8) out_relation_1 = rel_emb @ W_rel -> d_out; R2 = out_rel @ a_r2^T
    dim3 gor((200 + 63) / 64, (N_RELS + 63) / 64);
    k_mm<false><<<gor, TPB, 0, stream>>>(rel_emb, 100, W_rel, 200, out + 8000000, 200, N_RELS, 200, 100);
    k_mm<true><<<gor, TPB, 0, stream>>>(out + 8000000, 200, out_a + 400, 600, R2, 200, N_RELS, 200, 200);
    k_dotv<<<wave_blocks_474, TPB, 0, stream>>>(R2, out_a2, dR2, N_RELS, 200);

    // 9) layer-2 edge weights, mask, aggregation + final fuse
    k_edge2<<<edge_blocks, TPB, 0, stream>>>(tgt_el, src_el, edge_type, nhop, Qcat, dR2, w2);
    k_mask<<<(NB + TPB - 1) / TPB, TPB, 0, stream>>>(batch, mask);
    k_node2<<<wave_blocks_40000, TPB, 0, stream>>>(rowptr, eidx, src_el, edge_type, nhop,
                                                   Qcat, Pcat, R2, w2, mask, out);

    // 10) ortho scalar
    k_ortho<<<1, TPB, 0, stream>>>(att_a, out_a, out + 8094800);
}

// Round 4
// 601.066 us; speedup vs baseline: 1.8683x; 1.0962x over previous
//
#include <hip/hip_runtime.h>
#include <cstdint>
#include <cstddef>
#include <math.h>

#define N_NODES 40000
#define N_RELS  474
#define E0      100000
#define EN      30000
#define NE      130000
#define NB      8192
#define LRALPHA 0.2f

#define KP1 128   // padded K for layer-1 GEMM (K=100)
#define KP2 256   // padded K for layer-2 GEMM (K=200)
#define LD1 608   // Pcat row stride: [Pt0|Ps0|Pt1|Ps1|entW(200)|dots(4)|pad(4)]
#define LD2 416   // Qcat row stride: [Qt(200)|Qs(200)|dqt|dqs|pad(14)]

typedef __attribute__((ext_vector_type(8))) short short8;
typedef __attribute__((ext_vector_type(4))) float floatx4;

static __device__ __forceinline__ unsigned short f2bf(float f) {
    union { float f; uint32_t u; } v; v.f = f;
    uint32_t r = v.u + 0x7fff + ((v.u >> 16) & 1);
    return (unsigned short)(r >> 16);
}
static __device__ __forceinline__ float bf2f(unsigned short h) {
    union { uint32_t u; float f; } v; v.u = ((uint32_t)h) << 16;
    return v.f;
}

// ---------------- l2norm rows of ent -> bf16 padded [40000][KP1] ----------------
__global__ void k_l2norm_bf16(const float* __restrict__ in, unsigned short* __restrict__ out) {
    int w = (blockIdx.x * blockDim.x + threadIdx.x) >> 6;
    int lane = threadIdx.x & 63;
    if (w >= N_NODES) return;
    const float* r = in + (size_t)w * 100;
    float v0 = r[lane];
    int j1 = lane + 64;
    float v1 = (j1 < 100) ? r[j1] : 0.f;
    float ss = v0 * v0 + v1 * v1;
#pragma unroll
    for (int o = 32; o > 0; o >>= 1) ss += __shfl_down(ss, o);
    ss = __shfl(ss, 0);
    float inv = 1.f / fmaxf(sqrtf(ss), 1e-12f);
    unsigned short* dst = out + (size_t)w * KP1;
    dst[lane] = f2bf(v0 * inv);
    dst[j1] = (j1 < 100) ? f2bf(v1 * inv) : (unsigned short)0;
}

// ---------------- bf16 MFMA GEMM: C[m][n] = sum_k A[m][k] * B[n][k] ----------------
template <int KP>
__global__ __launch_bounds__(256) void k_gemm_mfma(const unsigned short* __restrict__ A,
                                                   const unsigned short* __restrict__ B,
                                                   unsigned short* __restrict__ C,
                                                   int ldc, int N) {
    constexpr int KSTEPS = KP / 32;
    int wave = threadIdx.x >> 6;
    int lane = threadIdx.x & 63;
    int quad = lane >> 4;
    int l16 = lane & 15;
    int m0 = blockIdx.x * 64 + wave * 16;
    int n_base = blockIdx.y * 128;
    short8 afrag[KSTEPS];
    const unsigned short* arow = A + (size_t)(m0 + l16) * KP + quad * 8;
#pragma unroll
    for (int ks = 0; ks < KSTEPS; ks++)
        afrag[ks] = *(const short8*)(arow + ks * 32);
    int ntiles = (N - n_base) >> 4;
    if (ntiles > 8) ntiles = 8;
    for (int t = 0; t < ntiles; t++) {
        int n0 = n_base + t * 16;
        const unsigned short* brow = B + (size_t)(n0 + l16) * KP + quad * 8;
        floatx4 acc = {0.f, 0.f, 0.f, 0.f};
#pragma unroll
        for (int ks = 0; ks < KSTEPS; ks++) {
            short8 bfrag = *(const short8*)(brow + ks * 32);
            acc = __builtin_amdgcn_mfma_f32_16x16x32_bf16(afrag[ks], bfrag, acc, 0, 0, 0);
        }
        unsigned short* cp = C + (size_t)(m0 + quad * 4) * ldc + n0 + l16;
        cp[0] = f2bf(acc[0]);
        cp[(size_t)ldc] = f2bf(acc[1]);
        cp[(size_t)2 * ldc] = f2bf(acc[2]);
        cp[(size_t)3 * ldc] = f2bf(acc[3]);
    }
}

// ---------------- u-vectors: u = a_part^T @ a2 ----------------
__global__ void k_uvec(const float* __restrict__ att_a, const float* __restrict__ att_a2,
                       const float* __restrict__ out_a, const float* __restrict__ out_a2,
                       float* __restrict__ uvecs) {
    int tid = blockIdx.x * blockDim.x + threadIdx.x;
    if (tid >= 800) return;
    float s = 0.f;
    if (tid < 400) {
        int v = tid / 100, k = tid % 100;
        int head = v >> 1, part = v & 1;
        const float* base = att_a + head * 30000 + part * 100 + k;
        const float* a2 = att_a2 + head * 100;
        for (int n = 0; n < 100; n++) s += a2[n] * base[n * 300];
        uvecs[tid] = s;
    } else {
        int v = (tid - 400) / 200, k = (tid - 400) % 200;
        const float* base = out_a + v * 200 + k;
        for (int n = 0; n < 200; n++) s += out_a2[n] * base[n * 600];
        uvecs[400 + v * 200 + k] = s;
    }
}

// ---------------- pack layer-1 B matrix: Wcat1 [608][KP1] bf16 ----------------
__global__ void k_pack1(const float* __restrict__ att_a, const float* __restrict__ W_ent,
                        const float* __restrict__ uvecs, unsigned short* __restrict__ W) {
    int idx = blockIdx.x * blockDim.x + threadIdx.x;
    if (idx >= 608 * KP1) return;
    int r = idx >> 7, k = idx & (KP1 - 1);
    float val = 0.f;
    if (k < 100) {
        if (r < 100)       val = att_a[r * 300 + k];
        else if (r < 200)  val = att_a[(r - 100) * 300 + 100 + k];
        else if (r < 300)  val = att_a[30000 + (r - 200) * 300 + k];
        else if (r < 400)  val = att_a[30000 + (r - 300) * 300 + 100 + k];
        else if (r < 600)  val = W_ent[k * 200 + (r - 400)];
        else if (r < 604)  val = uvecs[(r - 600) * 100 + k];
    }
    W[idx] = f2bf(val);
}

// ---------------- pack layer-2 B matrix: Wcat2 [416][KP2] bf16 ----------------
__global__ void k_pack2(const float* __restrict__ out_a, const float* __restrict__ uvecs,
                        unsigned short* __restrict__ W) {
    int idx = blockIdx.x * blockDim.x + threadIdx.x;
    if (idx >= 416 * KP2) return;
    int r = idx >> 8, k = idx & (KP2 - 1);
    float val = 0.f;
    if (k < 200) {
        if (r < 200)       val = out_a[r * 600 + k];
        else if (r < 400)  val = out_a[(r - 200) * 600 + 200 + k];
        else if (r == 400) val = uvecs[400 + k];
        else if (r == 401) val = uvecs[600 + k];
    }
    W[idx] = f2bf(val);
}

// ---------------- generic tiled fp32 matmul (474-row cases only) ----------------
template <bool BT>
__global__ __launch_bounds__(256) void k_mm(const float* __restrict__ A, int lda,
                                            const float* __restrict__ B, int ldb,
                                            float* __restrict__ C, int ldc,
                                            int M, int N, int K) {
    __shared__ float As[16][65];
    __shared__ float Bs[16][65];
    int tid = threadIdx.x;
    int tx = tid & 15, ty = tid >> 4;
    int m0 = blockIdx.y * 64, n0 = blockIdx.x * 64;
    float acc[4][4] = {};
    for (int k0 = 0; k0 < K; k0 += 16) {
        {
            int r = tid >> 2;
            int c4 = (tid & 3) * 4;
            int m = m0 + r;
#pragma unroll
            for (int u = 0; u < 4; u++) {
                int k = k0 + c4 + u;
                As[c4 + u][r] = (m < M && k < K) ? A[(size_t)m * lda + k] : 0.f;
            }
        }
        if (BT) {
            int r = tid >> 2;
            int c4 = (tid & 3) * 4;
            int n = n0 + r;
#pragma unroll
            for (int u = 0; u < 4; u++) {
                int k = k0 + c4 + u;
                Bs[c4 + u][r] = (n < N && k < K) ? B[(size_t)n * ldb + k] : 0.f;
            }
        } else {
            int kk = tid >> 4;
            int nn4 = (tid & 15) * 4;
            int k = k0 + kk;
#pragma unroll
            for (int u = 0; u < 4; u++) {
                int n = n0 + nn4 + u;
                Bs[kk][nn4 + u] = (k < K && n < N) ? B[(size_t)k * ldb + n] : 0.f;
            }
        }
        __syncthreads();
#pragma unroll
        for (int k = 0; k < 16; k++) {
            float a[4], b[4];
#pragma unroll
            for (int i = 0; i < 4; i++) a[i] = As[k][ty + 16 * i];
#pragma unroll
            for (int j = 0; j < 4; j++) b[j] = Bs[k][tx + 16 * j];
#pragma unroll
            for (int i = 0; i < 4; i++)
#pragma unroll
                for (int j = 0; j < 4; j++) acc[i][j] += a[i] * b[j];
        }
        __syncthreads();
    }
#pragma unroll
    for (int i = 0; i < 4; i++) {
        int m = m0 + ty + 16 * i;
        if (m >= M) continue;
#pragma unroll
        for (int j = 0; j < 4; j++) {
            int n = n0 + tx + 16 * j;
            if (n < N) C[(size_t)m * ldc + n] = acc[i][j];
        }
    }
}

// ---------------- per-row dot with vector (474-row cases) ----------------
__global__ void k_dotv(const float* __restrict__ mat, const float* __restrict__ vec,
                       float* __restrict__ out, int M, int F) {
    int w = (blockIdx.x * blockDim.x + threadIdx.x) >> 6;
    int lane = threadIdx.x & 63;
    if (w >= M) return;
    const float* r = mat + (size_t)w * F;
    float s = 0.f;
    for (int j = lane; j < F; j += 64) s += r[j] * vec[j];
#pragma unroll
    for (int o = 32; o > 0; o >>= 1) s += __shfl_down(s, o);
    if (lane == 0) out[w] = s;
}

// ---------------- CSR build ----------------
__global__ void k_hist(const int* __restrict__ tgt_el, const int* __restrict__ nhop,
                       int* __restrict__ deg) {
    int e = blockIdx.x * blockDim.x + threadIdx.x;
    if (e >= NE) return;
    int t = (e < E0) ? tgt_el[e] : nhop[(size_t)(e - E0) * 4 + 3];
    atomicAdd(&deg[t], 1);
}

__global__ void k_scan1(const int* __restrict__ deg, int* __restrict__ local,
                        int* __restrict__ bsums, int n) {
    int i = blockIdx.x * 256 + threadIdx.x;
    int v = (i < n) ? deg[i] : 0;
    int lane = threadIdx.x & 63;
    int wv = threadIdx.x >> 6;
    int x = v;
#pragma unroll
    for (int o = 1; o < 64; o <<= 1) {
        int t = __shfl_up(x, o);
        if (lane >= o) x += t;
    }
    __shared__ int wtot[4];
    if (lane == 63) wtot[wv] = x;
    __syncthreads();
    int add = 0;
    for (int k = 0; k < wv; k++) add += wtot[k];
    if (i < n) local[i] = add + x - v;
    if (threadIdx.x == 255) bsums[blockIdx.x] = add + x;
}

__global__ void k_scan2(int* __restrict__ bsums, int nb) {
    int tid = threadIdx.x;
    int v = (tid < nb) ? bsums[tid] : 0;
    int lane = tid & 63, wv = tid >> 6;
    int x = v;
#pragma unroll
    for (int o = 1; o < 64; o <<= 1) {
        int t = __shfl_up(x, o);
        if (lane >= o) x += t;
    }
    __shared__ int wtot[4];
    if (lane == 63) wtot[wv] = x;
    __syncthreads();
    int add = 0;
    for (int k = 0; k < wv; k++) add += wtot[k];
    __syncthreads();
    if (tid < nb) bsums[tid] = add + x - v;
    if (tid == 255) bsums[nb] = add + x;
}

__global__ void k_scan3(const int* __restrict__ local, const int* __restrict__ bsums,
                        int* __restrict__ rowptr, int* __restrict__ cursor, int n, int nb) {
    int i = blockIdx.x * 256 + threadIdx.x;
    if (i < n) {
        int v = local[i] + bsums[blockIdx.x];
        rowptr[i] = v;
        cursor[i] = v;
    } else if (i == n) {
        rowptr[n] = bsums[nb];
    }
}

__global__ void k_scatter(const int* __restrict__ tgt_el, const int* __restrict__ nhop,
                          int* __restrict__ cursor, int* __restrict__ eidx) {
    int e = blockIdx.x * blockDim.x + threadIdx.x;
    if (e >= NE) return;
    int t = (e < E0) ? tgt_el[e] : nhop[(size_t)(e - E0) * 4 + 3];
    int p = atomicAdd(&cursor[t], 1);
    eidx[p] = e;
}

// ---------------- per-edge attention scalar, layer 1 ----------------
__global__ void k_edge1(const int* __restrict__ tgt_el, const int* __restrict__ src_el,
                        const int* __restrict__ etype, const int* __restrict__ nhop,
                        const unsigned short* __restrict__ Pcat,
                        const float* __restrict__ dR0, const float* __restrict__ dR1,
                        float* __restrict__ w0, float* __restrict__ w1) {
    int e = blockIdx.x * blockDim.x + threadIdx.x;
    if (e >= NE) return;
    int t, s; float dr0, dr1;
    if (e < E0) {
        t = tgt_el[e]; s = src_el[e];
        int r = etype[e];
        dr0 = dR0[r]; dr1 = dR1[r];
    } else {
        const int* nh = nhop + (size_t)(e - E0) * 4;
        t = nh[3]; s = nh[0];
        dr0 = dR0[nh[1]] + dR0[nh[2]];
        dr1 = dR1[nh[1]] + dR1[nh[2]];
    }
    const unsigned short* pt = Pcat + (size_t)t * LD1 + 600;
    const unsigned short* ps = Pcat + (size_t)s * LD1 + 600;
    float p0 = bf2f(pt[0]) + bf2f(ps[1]) + dr0;
    float p1 = bf2f(pt[2]) + bf2f(ps[3]) + dr1;
    p0 = (p0 >= 0.f) ? p0 : LRALPHA * p0;
    p1 = (p1 >= 0.f) ? p1 : LRALPHA * p1;
    w0[e] = expf(-p0);
    w1[e] = expf(-p1);
}

// ---------------- per-edge attention scalar, layer 2 ----------------
__global__ void k_edge2(const int* __restrict__ tgt_el, const int* __restrict__ src_el,
                        const int* __restrict__ etype, const int* __restrict__ nhop,
                        const unsigned short* __restrict__ Qcat,
                        const float* __restrict__ dR2, float* __restrict__ w2) {
    int e = blockIdx.x * blockDim.x + threadIdx.x;
    if (e >= NE) return;
    int t, s; float dr;
    if (e < E0) {
        t = tgt_el[e]; s = src_el[e];
        dr = dR2[etype[e]];
    } else {
        const int* nh = nhop + (size_t)(e - E0) * 4;
        t = nh[3]; s = nh[0];
        dr = dR2[nh[1]] + dR2[nh[2]];
    }
    float p = bf2f(Qcat[(size_t)t * LD2 + 400]) + bf2f(Qcat[(size_t)s * LD2 + 401]) + dr;
    p = (p >= 0.f) ? p : LRALPHA * p;
    w2[e] = expf(-p);
}

// ---------------- node aggregation layer 1 (wave/node) -> x_bf16 [40000][KP2] ----------------
__global__ void k_node1(const int* __restrict__ rowptr, const int* __restrict__ eidx,
                        const int* __restrict__ src_el, const int* __restrict__ etype,
                        const int* __restrict__ nhop,
                        const unsigned short* __restrict__ Pcat,
                        const float* __restrict__ R10, const float* __restrict__ R11,
                        const float* __restrict__ w0, const float* __restrict__ w1,
                        unsigned short* __restrict__ x) {
    int node = (blockIdx.x * blockDim.x + threadIdx.x) >> 6;
    int lane = threadIdx.x & 63;
    if (node >= N_NODES) return;
    int j1 = lane + 64;
    bool v1 = (j1 < 100);
    float a00 = 0, a01 = 0, a10 = 0, a11 = 0, rs0 = 0, rs1 = 0;
    int beg = rowptr[node], end = rowptr[node + 1];
    for (int p = beg; p < end; p++) {
        int e = eidx[p];
        int s; float r00, r01, r10, r11;
        if (e < E0) {
            s = src_el[e];
            int t = etype[e];
            const float* q0 = R10 + (size_t)t * 100;
            const float* q1 = R11 + (size_t)t * 100;
            r00 = q0[lane]; r01 = v1 ? q0[j1] : 0.f;
            r10 = q1[lane]; r11 = v1 ? q1[j1] : 0.f;
        } else {
            const int* nh = nhop + (size_t)(e - E0) * 4;
            s = nh[0];
            const float* q0a = R10 + (size_t)nh[1] * 100;
            const float* q0b = R10 + (size_t)nh[2] * 100;
            const float* q1a = R11 + (size_t)nh[1] * 100;
            const float* q1b = R11 + (size_t)nh[2] * 100;
            r00 = q0a[lane] + q0b[lane]; r01 = v1 ? (q0a[j1] + q0b[j1]) : 0.f;
            r10 = q1a[lane] + q1b[lane]; r11 = v1 ? (q1a[j1] + q1b[j1]) : 0.f;
        }
        float W0 = w0[e], W1 = w1[e];
        rs0 += W0; rs1 += W1;
        const unsigned short* prow = Pcat + (size_t)s * LD1;
        a00 += W0 * (bf2f(prow[100 + lane]) + r00);
        a10 += W1 * (bf2f(prow[300 + lane]) + r10);
        if (v1) {
            a01 += W0 * (bf2f(prow[100 + j1]) + r01);
            a11 += W1 * (bf2f(prow[300 + j1]) + r11);
        }
    }
    float d0 = (rs0 == 0.f) ? 1e-12f : rs0;
    float d1 = (rs1 == 0.f) ? 1e-12f : rs1;
    const unsigned short* pn = Pcat + (size_t)node * LD1;
    unsigned short* xr = x + (size_t)node * KP2;
    float v = (a00 + rs0 * bf2f(pn[lane])) / d0;
    xr[lane] = f2bf((v > 0.f) ? v : expm1f(v));
    float u = (a10 + rs1 * bf2f(pn[200 + lane])) / d1;
    xr[100 + lane] = f2bf((u > 0.f) ? u : expm1f(u));
    if (v1) {
        float v2 = (a01 + rs0 * bf2f(pn[j1])) / d0;
        xr[j1] = f2bf((v2 > 0.f) ? v2 : expm1f(v2));
        float u2 = (a11 + rs1 * bf2f(pn[200 + j1])) / d1;
        xr[100 + j1] = f2bf((u2 > 0.f) ? u2 : expm1f(u2));
    }
    if (lane < KP2 - 200) xr[200 + lane] = 0;
}

// ---------------- node aggregation layer 2 + final fuse (wave/node) ----------------
__global__ void k_node2(const int* __restrict__ rowptr, const int* __restrict__ eidx,
                        const int* __restrict__ src_el, const int* __restrict__ etype,
                        const int* __restrict__ nhop,
                        const unsigned short* __restrict__ Qcat,
                        const unsigned short* __restrict__ Pcat,
                        const float* __restrict__ R2, const float* __restrict__ w2,
                        const float* __restrict__ mask,
                        float* __restrict__ out) {
    int node = (blockIdx.x * blockDim.x + threadIdx.x) >> 6;
    int lane = threadIdx.x & 63;
    if (node >= N_NODES) return;
    bool v3 = (lane < 8);
    int j3 = lane + 192;
    float acc0 = 0, acc1 = 0, acc2 = 0, acc3 = 0, rs = 0;
    int beg = rowptr[node], end = rowptr[node + 1];
    for (int p = beg; p < end; p++) {
        int e = eidx[p];
        int s; const float* ra; const float* rb = nullptr;
        if (e < E0) {
            s = src_el[e];
            ra = R2 + (size_t)etype[e] * 200;
        } else {
            const int* nh = nhop + (size_t)(e - E0) * 4;
            s = nh[0];
            ra = R2 + (size_t)nh[1] * 200;
            rb = R2 + (size_t)nh[2] * 200;
        }
        float W = w2[e]; rs += W;
        const unsigned short* qs = Qcat + (size_t)s * LD2 + 200;
        float r0 = ra[lane], r1 = ra[lane + 64], r2 = ra[lane + 128];
        float r3 = v3 ? ra[j3] : 0.f;
        if (rb) {
            r0 += rb[lane]; r1 += rb[lane + 64]; r2 += rb[lane + 128];
            if (v3) r3 += rb[j3];
        }
        acc0 += W * (bf2f(qs[lane]) + r0);
        acc1 += W * (bf2f(qs[lane + 64]) + r1);
        acc2 += W * (bf2f(qs[lane + 128]) + r2);
        if (v3) acc3 += W * (bf2f(qs[j3]) + r3);
    }
    float d = (rs == 0.f) ? 1e-12f : rs;
    const unsigned short* qt = Qcat + (size_t)node * LD2;
    const unsigned short* ew = Pcat + (size_t)node * LD1 + 400;
    float mk = mask[node];
    float val0 = bf2f(ew[lane])       + mk * ((acc0 + rs * bf2f(qt[lane])) / d);
    float val1 = bf2f(ew[lane + 64])  + mk * ((acc1 + rs * bf2f(qt[lane + 64])) / d);
    float val2 = bf2f(ew[lane + 128]) + mk * ((acc2 + rs * bf2f(qt[lane + 128])) / d);
    float val3 = v3 ? (bf2f(ew[j3]) + mk * ((acc3 + rs * bf2f(qt[j3])) / d)) : 0.f;
    float ss = val0 * val0 + val1 * val1 + val2 * val2 + val3 * val3;
#pragma unroll
    for (int o = 32; o > 0; o >>= 1) ss += __shfl_down(ss, o);
    ss = __shfl(ss, 0);
    float inv = 1.f / fmaxf(sqrtf(ss), 1e-12f);
    float* dst = out + (size_t)node * 200;
    dst[lane] = val0 * inv;
    dst[lane + 64] = val1 * inv;
    dst[lane + 128] = val2 * inv;
    if (v3) dst[j3] = val3 * inv;
}

// ---------------- mask scatter ----------------
__global__ void k_mask(const int* __restrict__ batch, float* __restrict__ mask) {
    int i = blockIdx.x * blockDim.x + threadIdx.x;
    if (i < NB) mask[batch[(size_t)i * 3 + 2]] = 1.0f;
}

// ---------------- ortho losses: parallel partial reduction ----------------
// flat index space [0, 90000): seg0 = att_a head0 (15000 pairs), seg1 = att_a head1,
// seg2 = out_a (60000 pairs). 9 accumulators: [seg*3 + {s0,s1,sc}]
__global__ void k_ortho_part(const float* __restrict__ att_a, const float* __restrict__ out_a,
                             float* __restrict__ accum) {
    float loc[9] = {0,0,0,0,0,0,0,0,0};
    int stride = gridDim.x * blockDim.x;
    for (int i = blockIdx.x * blockDim.x + threadIdx.x; i < 90000; i += stride) {
        int seg, li;
        const float* base;
        int L;
        if (i < 15000)      { seg = 0; li = i;          base = att_a;         L = 15000; }
        else if (i < 30000) { seg = 1; li = i - 15000;  base = att_a + 30000; L = 15000; }
        else                { seg = 2; li = i - 30000;  base = out_a;         L = 60000; }
        float a = base[li], b = base[L + li];
        loc[seg * 3 + 0] += a * a;
        loc[seg * 3 + 1] += b * b;
        loc[seg * 3 + 2] += a * b;
    }
    int lane = threadIdx.x & 63;
#pragma unroll
    for (int q = 0; q < 9; q++) {
        float s = loc[q];
#pragma unroll
        for (int o = 32; o > 0; o >>= 1) s += __shfl_down(s, o);
        if (lane == 0 && s != 0.f) atomicAdd(&accum[q], s);
    }
}

__global__ void k_ortho_fin(const float* __restrict__ accum, float* __restrict__ out_scalar) {
    if (threadIdx.x != 0 || blockIdx.x != 0) return;
    float total = 0.f;
#pragma unroll
    for (int m = 0; m < 3; m++) {
        float s0 = accum[m * 3 + 0], s1 = accum[m * 3 + 1], sc = accum[m * 3 + 2];
        float c = sc / (fmaxf(sqrtf(s0), 1e-12f) * fmaxf(sqrtf(s1), 1e-12f));
        total += 0.01f * 2.f * c * c;
    }
    out_scalar[0] = total;
}

// ---------------- launch ----------------
extern "C" void kernel_launch(void* const* d_in, const int* in_sizes, int n_in,
                              void* d_out, int out_size, void* d_ws, size_t ws_size,
                              hipStream_t stream) {
    const int* edge_list = (const int*)d_in[0];
    const int* edge_type = (const int*)d_in[1];
    const int* batch     = (const int*)d_in[2];
    const int* nhop      = (const int*)d_in[3];
    const float* ent_emb = (const float*)d_in[4];
    const float* rel_emb = (const float*)d_in[5];
    const float* W_ent   = (const float*)d_in[6];
    const float* W_rel   = (const float*)d_in[7];
    const float* att_a   = (const float*)d_in[8];
    const float* att_a2  = (const float*)d_in[9];
    const float* out_a   = (const float*)d_in[10];
    const float* out_a2  = (const float*)d_in[11];
    float* out = (float*)d_out;
    const int* tgt_el = edge_list;
    const int* src_el = edge_list + E0;

    char* ws = (char*)d_ws;
    size_t o = 0;
    auto alloc = [&](size_t nbytes) -> char* {
        char* p = ws + o;
        o += (nbytes + 255) & ~(size_t)255;
        return p;
    };
    unsigned short* ent_bf  = (unsigned short*)alloc((size_t)N_NODES * KP1 * 2);
    unsigned short* x_bf    = (unsigned short*)alloc((size_t)N_NODES * KP2 * 2);
    unsigned short* Pcat    = (unsigned short*)alloc((size_t)N_NODES * LD1 * 2);
    unsigned short* Qcat    = (unsigned short*)alloc((size_t)N_NODES * LD2 * 2);
    unsigned short* Wcat1   = (unsigned short*)alloc((size_t)608 * KP1 * 2);
    unsigned short* Wcat2   = (unsigned short*)alloc((size_t)416 * KP2 * 2);
    float* uvecs = (float*)alloc(800 * 4);
    float* R10   = (float*)alloc(474u * 100 * 4);
    float* R11   = (float*)alloc(474u * 100 * 4);
    float* R2    = (float*)alloc(474u * 200 * 4);
    float* dR10  = (float*)alloc(474u * 4);
    float* dR11  = (float*)alloc(474u * 4);
    float* dR2   = (float*)alloc(474u * 4);
    float* w0    = (float*)alloc((size_t)NE * 4);
    float* w1    = (float*)alloc((size_t)NE * 4);
    float* w2    = (float*)alloc((size_t)NE * 4);
    int* rowptr  = (int*)alloc((N_NODES + 1) * 4);
    int* cursor  = (int*)alloc(N_NODES * 4);
    int* eidx    = (int*)alloc((size_t)NE * 4);
    float* mask  = (float*)alloc(N_NODES * 4);
    int* scanloc = (int*)alloc(N_NODES * 4);
    int* bsums   = (int*)alloc(260 * 4);
    float* oacc  = (float*)alloc(9 * 4);

    const int TPB = 256;
    int wave_blocks_40000 = (N_NODES * 64 + TPB - 1) / TPB;   // 10000
    int wave_blocks_474   = (N_RELS * 64 + TPB - 1) / TPB;    // 119
    int edge_blocks       = (NE + TPB - 1) / TPB;
    int scan_blocks       = (N_NODES + 255) / 256;            // 157

    hipMemsetAsync(cursor, 0, N_NODES * 4, stream);
    hipMemsetAsync(mask, 0, N_NODES * 4, stream);
    hipMemsetAsync(oacc, 0, 9 * 4, stream);

    // 1) normalize entities -> bf16 padded
    k_l2norm_bf16<<<wave_blocks_40000, TPB, 0, stream>>>(ent_emb, ent_bf);

    // 2) CSR by target
    k_hist<<<edge_blocks, TPB, 0, stream>>>(tgt_el, nhop, cursor);
    k_scan1<<<scan_blocks, 256, 0, stream>>>(cursor, scanloc, bsums, N_NODES);
    k_scan2<<<1, 256, 0, stream>>>(bsums, scan_blocks);
    k_scan3<<<(N_NODES + 1 + 255) / 256, 256, 0, stream>>>(scanloc, bsums, rowptr, cursor, N_NODES, scan_blocks);
    k_scatter<<<edge_blocks, TPB, 0, stream>>>(tgt_el, nhop, cursor, eidx);

    // 3) pack fused B matrices
    k_uvec<<<4, 256, 0, stream>>>(att_a, att_a2, out_a, out_a2, uvecs);
    k_pack1<<<(608 * KP1 + 255) / 256, 256, 0, stream>>>(att_a, W_ent, uvecs, Wcat1);
    k_pack2<<<(416 * KP2 + 255) / 256, 256, 0, stream>>>(out_a, uvecs, Wcat2);

    // 4) fused layer-1 GEMM (MFMA bf16)
    k_gemm_mfma<KP1><<<dim3(625, 5), 256, 0, stream>>>(ent_bf, Wcat1, Pcat, LD1, 608);

    // 5) relation-side projections (fp32, tiny)
    dim3 gr1((100 + 63) / 64, (N_RELS + 63) / 64);
    k_mm<true><<<gr1, TPB, 0, stream>>>(rel_emb, 100, att_a + 200,   300, R10, 100, N_RELS, 100, 100);
    k_mm<true><<<gr1, TPB, 0, stream>>>(rel_emb, 100, att_a + 30200, 300, R11, 100, N_RELS, 100, 100);
    k_dotv<<<wave_blocks_474, TPB, 0, stream>>>(R10, att_a2,       dR10, N_RELS, 100);
    k_dotv<<<wave_blocks_474, TPB, 0, stream>>>(R11, att_a2 + 100, dR11, N_RELS, 100);

    // 6) layer-1 edge weights + aggregation -> x_bf16
    k_edge1<<<edge_blocks, TPB, 0, stream>>>(tgt_el, src_el, edge_type, nhop, Pcat, dR10, dR11, w0, w1);
    k_node1<<<wave_blocks_40000, TPB, 0, stream>>>(rowptr, eidx, src_el, edge_type, nhop,
                                                   Pcat, R10, R11, w0, w1, x_bf);

    // 7) fused layer-2 GEMM (MFMA bf16)
    k_gemm_mfma<KP2><<<dim3(625, 4), 256, 0, stream>>>(x_bf, Wcat2, Qcat, LD2, 416);

    // 8) out_relation_1 = rel_emb @ W_rel -> d_out; R2 = out_rel @ a_r2^T
    dim3 gor((200 + 63) / 64, (N_RELS + 63) / 64);
    k_mm<false><<<gor, TPB, 0, stream>>>(rel_emb, 100, W_rel, 200, out + 8000000, 200, N_RELS, 200, 100);
    k_mm<true><<<gor, TPB, 0, stream>>>(out + 8000000, 200, out_a + 400, 600, R2, 200, N_RELS, 200, 200);
    k_dotv<<<wave_blocks_474, TPB, 0, stream>>>(R2, out_a2, dR2, N_RELS, 200);

    // 9) layer-2 edge weights, mask, aggregation + final fuse
    k_edge2<<<edge_blocks, TPB, 0, stream>>>(tgt_el, src_el, edge_type, nhop, Qcat, dR2, w2);
    k_mask<<<(NB + TPB - 1) / TPB, TPB, 0, stream>>>(batch, mask);
    k_node2<<<wave_blocks_40000, TPB, 0, stream>>>(rowptr, eidx, src_el, edge_type, nhop,
                                                   Qcat, Pcat, R2, w2, mask, out);

    // 10) ortho scalar (parallel)
    k_ortho_part<<<128, 256, 0, stream>>>(att_a, out_a, oacc);
    k_ortho_fin<<<1, 64, 0, stream>>>(oacc, out + 8094800);
}

// Round 5
// 514.317 us; speedup vs baseline: 2.1834x; 1.1687x over previous
//
#include <hip/hip_runtime.h>
#include <cstdint>
#include <cstddef>
#include <math.h>

#define N_NODES 40000
#define N_RELS  474
#define E0      100000
#define EN      30000
#define NE      130000
#define NB      8192
#define LRALPHA 0.2f

#define KP1 128   // padded K for layer-1 GEMM (K=100)
#define KP2 256   // padded K for layer-2 GEMM (K=200)
// Pcat cols: [0:200) Pt interleaved (2f=h0,2f+1=h1) | [200:400) Ps interleaved |
//            [400:600) entW natural | [600:604) dots (u_t0,u_s0,u_t1,u_s1) | pad
#define LD1 608
// Qcat cols: [0:200) Qt | [200:400) Qs | 400 dqt | 401 dqs | pad
#define LD2 416

typedef __attribute__((ext_vector_type(8))) short short8;
typedef __attribute__((ext_vector_type(4))) float floatx4;

static __device__ __forceinline__ unsigned short f2bf(float f) {
    union { float f; uint32_t u; } v; v.f = f;
    uint32_t r = v.u + 0x7fff + ((v.u >> 16) & 1);
    return (unsigned short)(r >> 16);
}
static __device__ __forceinline__ float bf2f(unsigned short h) {
    union { uint32_t u; float f; } v; v.u = ((uint32_t)h) << 16;
    return v.f;
}
static __device__ __forceinline__ float bflo(uint32_t u) { return bf2f((unsigned short)(u & 0xffff)); }
static __device__ __forceinline__ float bfhi(uint32_t u) { return bf2f((unsigned short)(u >> 16)); }

// ---------------- l2norm rows of ent -> bf16 padded [40000][KP1] ----------------
__global__ void k_l2norm_bf16(const float* __restrict__ in, unsigned short* __restrict__ out) {
    int w = (blockIdx.x * blockDim.x + threadIdx.x) >> 6;
    int lane = threadIdx.x & 63;
    if (w >= N_NODES) return;
    const float* r = in + (size_t)w * 100;
    float v0 = r[lane];
    int j1 = lane + 64;
    float v1 = (j1 < 100) ? r[j1] : 0.f;
    float ss = v0 * v0 + v1 * v1;
#pragma unroll
    for (int o = 32; o > 0; o >>= 1) ss += __shfl_down(ss, o);
    ss = __shfl(ss, 0);
    float inv = 1.f / fmaxf(sqrtf(ss), 1e-12f);
    unsigned short* dst = out + (size_t)w * KP1;
    dst[lane] = f2bf(v0 * inv);
    dst[j1] = (j1 < 100) ? f2bf(v1 * inv) : (unsigned short)0;
}

// ---------------- bf16 MFMA GEMM: C[m][n] = sum_k A[m][k] * B[n][k] ----------------
template <int KP>
__global__ __launch_bounds__(256) void k_gemm_mfma(const unsigned short* __restrict__ A,
                                                   const unsigned short* __restrict__ B,
                                                   unsigned short* __restrict__ C,
                                                   int ldc, int N) {
    constexpr int KSTEPS = KP / 32;
    int wave = threadIdx.x >> 6;
    int lane = threadIdx.x & 63;
    int quad = lane >> 4;
    int l16 = lane & 15;
    int m0 = blockIdx.x * 64 + wave * 16;
    int n_base = blockIdx.y * 128;
    short8 afrag[KSTEPS];
    const unsigned short* arow = A + (size_t)(m0 + l16) * KP + quad * 8;
#pragma unroll
    for (int ks = 0; ks < KSTEPS; ks++)
        afrag[ks] = *(const short8*)(arow + ks * 32);
    int ntiles = (N - n_base) >> 4;
    if (ntiles > 8) ntiles = 8;
    for (int t = 0; t < ntiles; t++) {
        int n0 = n_base + t * 16;
        const unsigned short* brow = B + (size_t)(n0 + l16) * KP + quad * 8;
        floatx4 acc = {0.f, 0.f, 0.f, 0.f};
#pragma unroll
        for (int ks = 0; ks < KSTEPS; ks++) {
            short8 bfrag = *(const short8*)(brow + ks * 32);
            acc = __builtin_amdgcn_mfma_f32_16x16x32_bf16(afrag[ks], bfrag, acc, 0, 0, 0);
        }
        unsigned short* cp = C + (size_t)(m0 + quad * 4) * ldc + n0 + l16;
        cp[0] = f2bf(acc[0]);
        cp[(size_t)ldc] = f2bf(acc[1]);
        cp[(size_t)2 * ldc] = f2bf(acc[2]);
        cp[(size_t)3 * ldc] = f2bf(acc[3]);
    }
}

// ---------------- u-vectors: u = a_part^T @ a2 ----------------
// uvecs: [0:100)=u_t0 [100:200)=u_s0 [200:300)=u_t1 [300:400)=u_s1 [400:600)=u_t2 [600:800)=u_s2
__global__ void k_uvec(const float* __restrict__ att_a, const float* __restrict__ att_a2,
                       const float* __restrict__ out_a, const float* __restrict__ out_a2,
                       float* __restrict__ uvecs) {
    int tid = blockIdx.x * blockDim.x + threadIdx.x;
    if (tid >= 800) return;
    float s = 0.f;
    if (tid < 400) {
        int v = tid / 100, k = tid % 100;
        int head = v >> 1, part = v & 1;
        const float* base = att_a + head * 30000 + part * 100 + k;
        const float* a2 = att_a2 + head * 100;
        for (int n = 0; n < 100; n++) s += a2[n] * base[n * 300];
        uvecs[tid] = s;
    } else {
        int v = (tid - 400) / 200, k = (tid - 400) % 200;
        const float* base = out_a + v * 200 + k;
        for (int n = 0; n < 200; n++) s += out_a2[n] * base[n * 600];
        uvecs[400 + v * 200 + k] = s;
    }
}

// ---------------- pack layer-1 B matrix (interleaved Pt/Ps): Wcat1 [608][KP1] ----------------
__global__ void k_pack1(const float* __restrict__ att_a, const float* __restrict__ W_ent,
                        const float* __restrict__ uvecs, unsigned short* __restrict__ W) {
    int idx = blockIdx.x * blockDim.x + threadIdx.x;
    if (idx >= 608 * KP1) return;
    int r = idx >> 7, k = idx & (KP1 - 1);
    float val = 0.f;
    if (k < 100) {
        if (r < 200) {                       // Pt interleaved: col 2i+h = a_t head h row i
            int i = r >> 1, h = r & 1;
            val = att_a[h * 30000 + i * 300 + k];
        } else if (r < 400) {                // Ps interleaved
            int rr = r - 200, i = rr >> 1, h = rr & 1;
            val = att_a[h * 30000 + i * 300 + 100 + k];
        } else if (r < 600) {
            val = W_ent[k * 200 + (r - 400)];
        } else if (r < 604) {
            val = uvecs[(r - 600) * 100 + k];
        }
    }
    W[idx] = f2bf(val);
}

// ---------------- pack layer-2 B matrix (x is K-interleaved): Wcat2 [416][KP2] ----------------
__global__ void k_pack2(const float* __restrict__ out_a, const float* __restrict__ uvecs,
                        unsigned short* __restrict__ W) {
    int idx = blockIdx.x * blockDim.x + threadIdx.x;
    if (idx >= 416 * KP2) return;
    int r = idx >> 8, k = idx & (KP2 - 1);
    float val = 0.f;
    if (k < 200) {
        int klog = (k & 1) * 100 + (k >> 1);   // phys 2f=h0 feat f, 2f+1=h1 feat f
        if (r < 200)       val = out_a[r * 600 + klog];
        else if (r < 400)  val = out_a[(r - 200) * 600 + 200 + klog];
        else if (r == 400) val = uvecs[400 + klog];
        else if (r == 401) val = uvecs[600 + klog];
    }
    W[idx] = f2bf(val);
}

// ---------------- R1 interleaved projection: R1i[474][200], (R10[f],R11[f]) pairs ------------
__global__ void k_relproj1(const float* __restrict__ rel_emb, const float* __restrict__ att_a,
                           float* __restrict__ R1i) {
    int w = (blockIdx.x * blockDim.x + threadIdx.x) >> 6;
    int lane = threadIdx.x & 63;
    if (w >= N_RELS) return;
    const float* re = rel_emb + (size_t)w * 100;
    float2* dst = (float2*)(R1i + (size_t)w * 200);
    for (int f = lane; f < 100; f += 64) {
        const float* a0 = att_a + f * 300 + 200;
        const float* a1 = att_a + 30000 + f * 300 + 200;
        float s0 = 0.f, s1 = 0.f;
        for (int k = 0; k < 100; k++) {
            float rk = re[k];
            s0 += rk * a0[k];
            s1 += rk * a1[k];
        }
        dst[f] = make_float2(s0, s1);
    }
}

// dR1h[r] = R1h[r] . a2_h
__global__ void k_dR1(const float* __restrict__ R1i, const float* __restrict__ att_a2,
                      float* __restrict__ dR10, float* __restrict__ dR11) {
    int w = (blockIdx.x * blockDim.x + threadIdx.x) >> 6;
    int lane = threadIdx.x & 63;
    if (w >= N_RELS) return;
    const float2* row = (const float2*)(R1i + (size_t)w * 200);
    float s0 = 0.f, s1 = 0.f;
    for (int f = lane; f < 100; f += 64) {
        float2 v = row[f];
        s0 += v.x * att_a2[f];
        s1 += v.y * att_a2[100 + f];
    }
#pragma unroll
    for (int o = 32; o > 0; o >>= 1) {
        s0 += __shfl_down(s0, o);
        s1 += __shfl_down(s1, o);
    }
    if (lane == 0) { dR10[w] = s0; dR11[w] = s1; }
}

// ---------------- generic tiled fp32 matmul (474-row cases only) ----------------
template <bool BT>
__global__ __launch_bounds__(256) void k_mm(const float* __restrict__ A, int lda,
                                            const float* __restrict__ B, int ldb,
                                            float* __restrict__ C, int ldc,
                                            int M, int N, int K) {
    __shared__ float As[16][65];
    __shared__ float Bs[16][65];
    int tid = threadIdx.x;
    int tx = tid & 15, ty = tid >> 4;
    int m0 = blockIdx.y * 64, n0 = blockIdx.x * 64;
    float acc[4][4] = {};
    for (int k0 = 0; k0 < K; k0 += 16) {
        {
            int r = tid >> 2;
            int c4 = (tid & 3) * 4;
            int m = m0 + r;
#pragma unroll
            for (int u = 0; u < 4; u++) {
                int k = k0 + c4 + u;
                As[c4 + u][r] = (m < M && k < K) ? A[(size_t)m * lda + k] : 0.f;
            }
        }
        if (BT) {
            int r = tid >> 2;
            int c4 = (tid & 3) * 4;
            int n = n0 + r;
#pragma unroll
            for (int u = 0; u < 4; u++) {
                int k = k0 + c4 + u;
                Bs[c4 + u][r] = (n < N && k < K) ? B[(size_t)n * ldb + k] : 0.f;
            }
        } else {
            int kk = tid >> 4;
            int nn4 = (tid & 15) * 4;
            int k = k0 + kk;
#pragma unroll
            for (int u = 0; u < 4; u++) {
                int n = n0 + nn4 + u;
                Bs[kk][nn4 + u] = (k < K && n < N) ? B[(size_t)k * ldb + n] : 0.f;
            }
        }
        __syncthreads();
#pragma unroll
        for (int k = 0; k < 16; k++) {
            float a[4], b[4];
#pragma unroll
            for (int i = 0; i < 4; i++) a[i] = As[k][ty + 16 * i];
#pragma unroll
            for (int j = 0; j < 4; j++) b[j] = Bs[k][tx + 16 * j];
#pragma unroll
            for (int i = 0; i < 4; i++)
#pragma unroll
                for (int j = 0; j < 4; j++) acc[i][j] += a[i] * b[j];
        }
        __syncthreads();
    }
#pragma unroll
    for (int i = 0; i < 4; i++) {
        int m = m0 + ty + 16 * i;
        if (m >= M) continue;
#pragma unroll
        for (int j = 0; j < 4; j++) {
            int n = n0 + tx + 16 * j;
            if (n < N) C[(size_t)m * ldc + n] = acc[i][j];
        }
    }
}

// ---------------- per-row dot with vector (474-row cases) ----------------
__global__ void k_dotv(const float* __restrict__ mat, const float* __restrict__ vec,
                       float* __restrict__ out, int M, int F) {
    int w = (blockIdx.x * blockDim.x + threadIdx.x) >> 6;
    int lane = threadIdx.x & 63;
    if (w >= M) return;
    const float* r = mat + (size_t)w * F;
    float s = 0.f;
    for (int j = lane; j < F; j += 64) s += r[j] * vec[j];
#pragma unroll
    for (int o = 32; o > 0; o >>= 1) s += __shfl_down(s, o);
    if (lane == 0) out[w] = s;
}

// ---------------- CSR build ----------------
__global__ void k_hist(const int* __restrict__ tgt_el, const int* __restrict__ nhop,
                       int* __restrict__ deg) {
    int e = blockIdx.x * blockDim.x + threadIdx.x;
    if (e >= NE) return;
    int t = (e < E0) ? tgt_el[e] : nhop[(size_t)(e - E0) * 4 + 3];
    atomicAdd(&deg[t], 1);
}

__global__ void k_scan1(const int* __restrict__ deg, int* __restrict__ local,
                        int* __restrict__ bsums, int n) {
    int i = blockIdx.x * 256 + threadIdx.x;
    int v = (i < n) ? deg[i] : 0;
    int lane = threadIdx.x & 63;
    int wv = threadIdx.x >> 6;
    int x = v;
#pragma unroll
    for (int o = 1; o < 64; o <<= 1) {
        int t = __shfl_up(x, o);
        if (lane >= o) x += t;
    }
    __shared__ int wtot[4];
    if (lane == 63) wtot[wv] = x;
    __syncthreads();
    int add = 0;
    for (int k = 0; k < wv; k++) add += wtot[k];
    if (i < n) local[i] = add + x - v;
    if (threadIdx.x == 255) bsums[blockIdx.x] = add + x;
}

__global__ void k_scan2(int* __restrict__ bsums, int nb) {
    int tid = threadIdx.x;
    int v = (tid < nb) ? bsums[tid] : 0;
    int lane = tid & 63, wv = tid >> 6;
    int x = v;
#pragma unroll
    for (int o = 1; o < 64; o <<= 1) {
        int t = __shfl_up(x, o);
        if (lane >= o) x += t;
    }
    __shared__ int wtot[4];
    if (lane == 63) wtot[wv] = x;
    __syncthreads();
    int add = 0;
    for (int k = 0; k < wv; k++) add += wtot[k];
    __syncthreads();
    if (tid < nb) bsums[tid] = add + x - v;
    if (tid == 255) bsums[nb] = add + x;
}

__global__ void k_scan3(const int* __restrict__ local, const int* __restrict__ bsums,
                        int* __restrict__ rowptr, int* __restrict__ cursor, int n, int nb) {
    int i = blockIdx.x * 256 + threadIdx.x;
    if (i < n) {
        int v = local[i] + bsums[blockIdx.x];
        rowptr[i] = v;
        cursor[i] = v;
    } else if (i == n) {
        rowptr[n] = bsums[nb];
    }
}

// scatter edge payloads into CSR order
__global__ void k_scatter(const int* __restrict__ tgt_el, const int* __restrict__ src_el,
                          const int* __restrict__ etype, const int* __restrict__ nhop,
                          int* __restrict__ cursor,
                          int* __restrict__ tgts, int* __restrict__ srcs,
                          int2* __restrict__ relpk) {
    int e = blockIdx.x * blockDim.x + threadIdx.x;
    if (e >= NE) return;
    int t, s, r1, r2;
    if (e < E0) {
        t = tgt_el[e]; s = src_el[e]; r1 = etype[e]; r2 = -1;
    } else {
        const int* nh = nhop + (size_t)(e - E0) * 4;
        t = nh[3]; s = nh[0]; r1 = nh[1]; r2 = nh[2];
    }
    int p = atomicAdd(&cursor[t], 1);
    tgts[p] = t; srcs[p] = s;
    relpk[p] = make_int2(r1, r2);
}

// ---------------- per-edge attention scalars (CSR-position order) ----------------
__global__ void k_edge1(const int* __restrict__ tgts, const int* __restrict__ srcs,
                        const int2* __restrict__ relpk,
                        const unsigned short* __restrict__ Pcat,
                        const float* __restrict__ dR10, const float* __restrict__ dR11,
                        float2* __restrict__ wpair) {
    int p = blockIdx.x * blockDim.x + threadIdx.x;
    if (p >= NE) return;
    int t = tgts[p], s = srcs[p];
    int2 rp = relpk[p];
    float dr0 = dR10[rp.x], dr1 = dR11[rp.x];
    if (rp.y >= 0) { dr0 += dR10[rp.y]; dr1 += dR11[rp.y]; }
    uint2 td = *(const uint2*)(Pcat + (size_t)t * LD1 + 600);   // (u_t0,u_s0),(u_t1,u_s1)
    uint2 sd = *(const uint2*)(Pcat + (size_t)s * LD1 + 600);
    float p0 = bflo(td.x) + bfhi(sd.x) + dr0;
    float p1 = bflo(td.y) + bfhi(sd.y) + dr1;
    p0 = (p0 >= 0.f) ? p0 : LRALPHA * p0;
    p1 = (p1 >= 0.f) ? p1 : LRALPHA * p1;
    wpair[p] = make_float2(expf(-p0), expf(-p1));
}

__global__ void k_edge2(const int* __restrict__ tgts, const int* __restrict__ srcs,
                        const int2* __restrict__ relpk,
                        const unsigned short* __restrict__ Qcat,
                        const float* __restrict__ dR2, float* __restrict__ w2) {
    int p = blockIdx.x * blockDim.x + threadIdx.x;
    if (p >= NE) return;
    int t = tgts[p], s = srcs[p];
    int2 rp = relpk[p];
    float dr = dR2[rp.x];
    if (rp.y >= 0) dr += dR2[rp.y];
    uint32_t tq = *(const uint32_t*)(Qcat + (size_t)t * LD2 + 400);  // (dqt, dqs)
    uint32_t sq = *(const uint32_t*)(Qcat + (size_t)s * LD2 + 400);
    float pp = bflo(tq) + bfhi(sq) + dr;
    pp = (pp >= 0.f) ? pp : LRALPHA * pp;
    w2[p] = expf(-pp);
}

// ---------------- node aggregation layer 1 (wave/node) -> x bf16 K-interleaved --------------
__global__ void k_node1(const int* __restrict__ rowptr, const int* __restrict__ srcs,
                        const int2* __restrict__ relpk, const float2* __restrict__ wpair,
                        const unsigned short* __restrict__ Pcat,
                        const float* __restrict__ R1i,
                        unsigned short* __restrict__ x) {
    int node = (blockIdx.x * blockDim.x + threadIdx.x) >> 6;
    int lane = threadIdx.x & 63;
    if (node >= N_NODES) return;
    int f0 = lane, f1 = lane + 64;
    bool v1 = (f1 < 100);
    float b00 = 0, b01 = 0, b10 = 0, b11 = 0, rs0 = 0, rs1 = 0;
    int beg = rowptr[node], end = rowptr[node + 1];
    for (int p = beg; p < end; p++) {
        int s = srcs[p];
        int2 rp = relpk[p];
        float2 w = wpair[p];
        const float2* r1a = (const float2*)(R1i + (size_t)rp.x * 200);
        float2 ra0 = r1a[f0];
        float2 ra1 = v1 ? r1a[f1] : make_float2(0.f, 0.f);
        if (rp.y >= 0) {
            const float2* r1b = (const float2*)(R1i + (size_t)rp.y * 200);
            float2 t0 = r1b[f0];
            ra0.x += t0.x; ra0.y += t0.y;
            if (v1) { float2 t1 = r1b[f1]; ra1.x += t1.x; ra1.y += t1.y; }
        }
        const unsigned short* prow = Pcat + (size_t)s * LD1 + 200;
        uint32_t ps0 = *(const uint32_t*)(prow + 2 * f0);
        rs0 += w.x; rs1 += w.y;
        b00 += w.x * (bflo(ps0) + ra0.x);
        b01 += w.y * (bfhi(ps0) + ra0.y);
        if (v1) {
            uint32_t ps1 = *(const uint32_t*)(prow + 2 * f1);
            b10 += w.x * (bflo(ps1) + ra1.x);
            b11 += w.y * (bfhi(ps1) + ra1.y);
        }
    }
    float d0 = (rs0 == 0.f) ? 1e-12f : rs0;
    float d1 = (rs1 == 0.f) ? 1e-12f : rs1;
    const unsigned short* pn = Pcat + (size_t)node * LD1;
    unsigned short* xr = x + (size_t)node * KP2;
    {
        uint32_t pt = *(const uint32_t*)(pn + 2 * f0);
        float v = (b00 + rs0 * bflo(pt)) / d0;
        float u = (b01 + rs1 * bfhi(pt)) / d1;
        v = (v > 0.f) ? v : expm1f(v);
        u = (u > 0.f) ? u : expm1f(u);
        *(uint32_t*)(xr + 2 * f0) = (uint32_t)f2bf(v) | ((uint32_t)f2bf(u) << 16);
    }
    if (v1) {
        uint32_t pt = *(const uint32_t*)(pn + 2 * f1);
        float v = (b10 + rs0 * bflo(pt)) / d0;
        float u = (b11 + rs1 * bfhi(pt)) / d1;
        v = (v > 0.f) ? v : expm1f(v);
        u = (u > 0.f) ? u : expm1f(u);
        *(uint32_t*)(xr + 2 * f1) = (uint32_t)f2bf(v) | ((uint32_t)f2bf(u) << 16);
    }
    if (lane < (KP2 - 200) / 2) *(uint32_t*)(xr + 200 + 2 * lane) = 0;
}

// ---------------- node aggregation layer 2 + final fuse (wave/node) ----------------
__global__ void k_node2(const int* __restrict__ rowptr, const int* __restrict__ srcs,
                        const int2* __restrict__ relpk, const float* __restrict__ w2,
                        const unsigned short* __restrict__ Qcat,
                        const unsigned short* __restrict__ Pcat,
                        const float* __restrict__ R2, const float* __restrict__ mask,
                        float* __restrict__ out) {
    int node = (blockIdx.x * blockDim.x + threadIdx.x) >> 6;
    int lane = threadIdx.x & 63;
    if (node >= N_NODES) return;
    int q0 = lane, q1 = lane + 64;      // feature pairs (2q, 2q+1); 100 pairs
    bool v = (q1 < 100);
    float c00 = 0, c01 = 0, c10 = 0, c11 = 0, rs = 0;
    int beg = rowptr[node], end = rowptr[node + 1];
    for (int p = beg; p < end; p++) {
        int s = srcs[p];
        int2 rp = relpk[p];
        float W = w2[p];
        const float* r2r = R2 + (size_t)rp.x * 200;
        float2 ra = *(const float2*)(r2r + 2 * q0);
        float2 rb = v ? *(const float2*)(r2r + 2 * q1) : make_float2(0.f, 0.f);
        if (rp.y >= 0) {
            const float* r2b = R2 + (size_t)rp.y * 200;
            float2 t0 = *(const float2*)(r2b + 2 * q0);
            ra.x += t0.x; ra.y += t0.y;
            if (v) { float2 t1 = *(const float2*)(r2b + 2 * q1); rb.x += t1.x; rb.y += t1.y; }
        }
        const unsigned short* qsrow = Qcat + (size_t)s * LD2 + 200;
        uint32_t qa = *(const uint32_t*)(qsrow + 2 * q0);
        rs += W;
        c00 += W * (bflo(qa) + ra.x);
        c01 += W * (bfhi(qa) + ra.y);
        if (v) {
            uint32_t qb = *(const uint32_t*)(qsrow + 2 * q1);
            c10 += W * (bflo(qb) + rb.x);
            c11 += W * (bfhi(qb) + rb.y);
        }
    }
    float d = (rs == 0.f) ? 1e-12f : rs;
    const unsigned short* qt = Qcat + (size_t)node * LD2;
    const unsigned short* ew = Pcat + (size_t)node * LD1 + 400;
    float mk = mask[node];
    uint32_t t0 = *(const uint32_t*)(qt + 2 * q0);
    uint32_t e0 = *(const uint32_t*)(ew + 2 * q0);
    float val00 = bflo(e0) + mk * ((c00 + rs * bflo(t0)) / d);
    float val01 = bfhi(e0) + mk * ((c01 + rs * bfhi(t0)) / d);
    float val10 = 0.f, val11 = 0.f;
    if (v) {
        uint32_t t1 = *(const uint32_t*)(qt + 2 * q1);
        uint32_t e1 = *(const uint32_t*)(ew + 2 * q1);
        val10 = bflo(e1) + mk * ((c10 + rs * bflo(t1)) / d);
        val11 = bfhi(e1) + mk * ((c11 + rs * bfhi(t1)) / d);
    }
    float ss = val00 * val00 + val01 * val01 + val10 * val10 + val11 * val11;
#pragma unroll
    for (int o = 32; o > 0; o >>= 1) ss += __shfl_down(ss, o);
    ss = __shfl(ss, 0);
    float inv = 1.f / fmaxf(sqrtf(ss), 1e-12f);
    float* dst = out + (size_t)node * 200;
    *(float2*)(dst + 2 * q0) = make_float2(val00 * inv, val01 * inv);
    if (v) *(float2*)(dst + 2 * q1) = make_float2(val10 * inv, val11 * inv);
}

// ---------------- mask scatter ----------------
__global__ void k_mask(const int* __restrict__ batch, float* __restrict__ mask) {
    int i = blockIdx.x * blockDim.x + threadIdx.x;
    if (i < NB) mask[batch[(size_t)i * 3 + 2]] = 1.0f;
}

// ---------------- ortho losses: parallel partial reduction ----------------
__global__ void k_ortho_part(const float* __restrict__ att_a, const float* __restrict__ out_a,
                             float* __restrict__ accum) {
    float loc[9] = {0,0,0,0,0,0,0,0,0};
    int stride = gridDim.x * blockDim.x;
    for (int i = blockIdx.x * blockDim.x + threadIdx.x; i < 90000; i += stride) {
        int seg, li;
        const float* base;
        int L;
        if (i < 15000)      { seg = 0; li = i;          base = att_a;         L = 15000; }
        else if (i < 30000) { seg = 1; li = i - 15000;  base = att_a + 30000; L = 15000; }
        else                { seg = 2; li = i - 30000;  base = out_a;         L = 60000; }
        float a = base[li], b = base[L + li];
        loc[seg * 3 + 0] += a * a;
        loc[seg * 3 + 1] += b * b;
        loc[seg * 3 + 2] += a * b;
    }
    int lane = threadIdx.x & 63;
#pragma unroll
    for (int q = 0; q < 9; q++) {
        float s = loc[q];
#pragma unroll
        for (int o = 32; o > 0; o >>= 1) s += __shfl_down(s, o);
        if (lane == 0 && s != 0.f) atomicAdd(&accum[q], s);
    }
}

__global__ void k_ortho_fin(const float* __restrict__ accum, float* __restrict__ out_scalar) {
    if (threadIdx.x != 0 || blockIdx.x != 0) return;
    float total = 0.f;
#pragma unroll
    for (int m = 0; m < 3; m++) {
        float s0 = accum[m * 3 + 0], s1 = accum[m * 3 + 1], sc = accum[m * 3 + 2];
        float c = sc / (fmaxf(sqrtf(s0), 1e-12f) * fmaxf(sqrtf(s1), 1e-12f));
        total += 0.01f * 2.f * c * c;
    }
    out_scalar[0] = total;
}

// ---------------- launch ----------------
extern "C" void kernel_launch(void* const* d_in, const int* in_sizes, int n_in,
                              void* d_out, int out_size, void* d_ws, size_t ws_size,
                              hipStream_t stream) {
    const int* edge_list = (const int*)d_in[0];
    const int* edge_type = (const int*)d_in[1];
    const int* batch     = (const int*)d_in[2];
    const int* nhop      = (const int*)d_in[3];
    const float* ent_emb = (const float*)d_in[4];
    const float* rel_emb = (const float*)d_in[5];
    const float* W_ent   = (const float*)d_in[6];
    const float* W_rel   = (const float*)d_in[7];
    const float* att_a   = (const float*)d_in[8];
    const float* att_a2  = (const float*)d_in[9];
    const float* out_a   = (const float*)d_in[10];
    const float* out_a2  = (const float*)d_in[11];
    float* out = (float*)d_out;
    const int* tgt_el = edge_list;
    const int* src_el = edge_list + E0;

    char* ws = (char*)d_ws;
    size_t o = 0;
    auto alloc = [&](size_t nbytes) -> char* {
        char* p = ws + o;
        o += (nbytes + 255) & ~(size_t)255;
        return p;
    };
    unsigned short* ent_bf  = (unsigned short*)alloc((size_t)N_NODES * KP1 * 2);
    unsigned short* x_bf    = (unsigned short*)alloc((size_t)N_NODES * KP2 * 2);
    unsigned short* Pcat    = (unsigned short*)alloc((size_t)N_NODES * LD1 * 2);
    unsigned short* Qcat    = (unsigned short*)alloc((size_t)N_NODES * LD2 * 2);
    unsigned short* Wcat1   = (unsigned short*)alloc((size_t)608 * KP1 * 2);
    unsigned short* Wcat2   = (unsigned short*)alloc((size_t)416 * KP2 * 2);
    float* uvecs = (float*)alloc(800 * 4);
    float* R1i   = (float*)alloc(474u * 200 * 4);
    float* R2    = (float*)alloc(474u * 200 * 4);
    float* dR10  = (float*)alloc(474u * 4);
    float* dR11  = (float*)alloc(474u * 4);
    float* dR2   = (float*)alloc(474u * 4);
    float2* wpair = (float2*)alloc((size_t)NE * 8);
    float* w2    = (float*)alloc((size_t)NE * 4);
    int* rowptr  = (int*)alloc((N_NODES + 1) * 4);
    int* cursor  = (int*)alloc(N_NODES * 4);
    int* tgts    = (int*)alloc((size_t)NE * 4);
    int* srcs    = (int*)alloc((size_t)NE * 4);
    int2* relpk  = (int2*)alloc((size_t)NE * 8);
    float* mask  = (float*)alloc(N_NODES * 4);
    int* scanloc = (int*)alloc(N_NODES * 4);
    int* bsums   = (int*)alloc(260 * 4);
    float* oacc  = (float*)alloc(9 * 4);

    const int TPB = 256;
    int wave_blocks_40000 = (N_NODES * 64 + TPB - 1) / TPB;   // 10000
    int wave_blocks_474   = (N_RELS * 64 + TPB - 1) / TPB;    // 119
    int edge_blocks       = (NE + TPB - 1) / TPB;
    int scan_blocks       = (N_NODES + 255) / 256;            // 157

    hipMemsetAsync(cursor, 0, N_NODES * 4, stream);
    hipMemsetAsync(mask, 0, N_NODES * 4, stream);
    hipMemsetAsync(oacc, 0, 9 * 4, stream);

    // 1) normalize entities -> bf16 padded
    k_l2norm_bf16<<<wave_blocks_40000, TPB, 0, stream>>>(ent_emb, ent_bf);

    // 2) CSR by target, payloads in CSR order
    k_hist<<<edge_blocks, TPB, 0, stream>>>(tgt_el, nhop, cursor);
    k_scan1<<<scan_blocks, 256, 0, stream>>>(cursor, scanloc, bsums, N_NODES);
    k_scan2<<<1, 256, 0, stream>>>(bsums, scan_blocks);
    k_scan3<<<(N_NODES + 1 + 255) / 256, 256, 0, stream>>>(scanloc, bsums, rowptr, cursor, N_NODES, scan_blocks);
    k_scatter<<<edge_blocks, TPB, 0, stream>>>(tgt_el, src_el, edge_type, nhop, cursor,
                                               tgts, srcs, relpk);

    // 3) pack fused B matrices
    k_uvec<<<4, 256, 0, stream>>>(att_a, att_a2, out_a, out_a2, uvecs);
    k_pack1<<<(608 * KP1 + 255) / 256, 256, 0, stream>>>(att_a, W_ent, uvecs, Wcat1);
    k_pack2<<<(416 * KP2 + 255) / 256, 256, 0, stream>>>(out_a, uvecs, Wcat2);

    // 4) fused layer-1 GEMM (MFMA bf16)
    k_gemm_mfma<KP1><<<dim3(625, 5), 256, 0, stream>>>(ent_bf, Wcat1, Pcat, LD1, 608);

    // 5) relation-side projections (interleaved) + dots
    k_relproj1<<<wave_blocks_474, TPB, 0, stream>>>(rel_emb, att_a, R1i);
    k_dR1<<<wave_blocks_474, TPB, 0, stream>>>(R1i, att_a2, dR10, dR11);

    // 6) layer-1 edge weights + aggregation -> x_bf (K-interleaved)
    k_edge1<<<edge_blocks, TPB, 0, stream>>>(tgts, srcs, relpk, Pcat, dR10, dR11, wpair);
    k_node1<<<wave_blocks_40000, TPB, 0, stream>>>(rowptr, srcs, relpk, wpair, Pcat, R1i, x_bf);

    // 7) fused layer-2 GEMM (MFMA bf16)
    k_gemm_mfma<KP2><<<dim3(625, 4), 256, 0, stream>>>(x_bf, Wcat2, Qcat, LD2, 416);

    // 8) out_relation_1 = rel_emb @ W_rel -> d_out; R2 = out_rel1 @ a_r2^T; dR2
    dim3 gor((200 + 63) / 64, (N_RELS + 63) / 64);
    k_mm<false><<<gor, TPB, 0, stream>>>(rel_emb, 100, W_rel, 200, out + 8000000, 200, N_RELS, 200, 100);
    k_mm<true><<<gor, TPB, 0, stream>>>(out + 8000000, 200, out_a + 400, 600, R2, 200, N_RELS, 200, 200);
    k_dotv<<<wave_blocks_474, TPB, 0, stream>>>(R2, out_a2, dR2, N_RELS, 200);

    // 9) layer-2 edge weights, mask, aggregation + final fuse
    k_edge2<<<edge_blocks, TPB, 0, stream>>>(tgts, srcs, relpk, Qcat, dR2, w2);
    k_mask<<<(NB + TPB - 1) / TPB, TPB, 0, stream>>>(batch, mask);
    k_node2<<<wave_blocks_40000, TPB, 0, stream>>>(rowptr, srcs, relpk, w2, Qcat, Pcat, R2, mask, out);

    // 10) ortho scalar (parallel)
    k_ortho_part<<<128, 256, 0, stream>>>(att_a, out_a, oacc);
    k_ortho_fin<<<1, 64, 0, stream>>>(oacc, out + 8094800);
}